// Round 1
// baseline (1044.469 us; speedup 1.0000x reference)
//
#include <hip/hip_runtime.h>
#include <hip/hip_bf16.h>

#define DI __device__ __forceinline__

typedef __attribute__((ext_vector_type(8))) short short8;
typedef __attribute__((ext_vector_type(4))) float f32x4;

DI unsigned short f2bf(float f) {
    union { float f; unsigned int u; } v; v.f = f;
    unsigned int r = v.u + 0x7FFFu + ((v.u >> 16) & 1u);
    return (unsigned short)(r >> 16);
}
DI float bf2f(unsigned short h) {
    union { unsigned int u; float f; } v; v.u = ((unsigned int)h) << 16;
    return v.f;
}

#define GLD16(g, l) __builtin_amdgcn_global_load_lds( \
    (const __attribute__((address_space(1))) void*)(g), \
    (__attribute__((address_space(3))) void*)(l), 16, 0, 0)

// ---------------------------------------------------------------------------
// NT GEMM: C[i][j] = sum_k A[i][k] * Bt[j][k]   (128x128 tile, BK=32, 4 waves)
// EPI: 0 = +bias -> bf16 out, 1 = *scale+mask -> bf16, 2 = plain bf16, 3 = +bias -> f32
// ---------------------------------------------------------------------------
template<int EPI>
__global__ __launch_bounds__(256) void gemm_nt(
    const unsigned short* __restrict__ A, const unsigned short* __restrict__ Bt,
    void* __restrict__ Cout, const float* __restrict__ bias,
    const int* __restrict__ mask, int K, int lda, int ldb, int ldc,
    long sA, long sB, long sC, long sM, float scale)
{
    const int z = blockIdx.z;
    A  += (long)z * sA;
    Bt += (long)z * sB;
    const int bm = blockIdx.x * 128, bn = blockIdx.y * 128;
    const int tid = threadIdx.x, wave = tid >> 6, lane = tid & 63;
    const int wr = wave >> 1, wc = wave & 1;

    __shared__ unsigned short As[128 * 32];
    __shared__ unsigned short Bs[128 * 32];

    const unsigned short* ag = A + (size_t)(bm + wave * 16 + (lane >> 2)) * lda + (lane & 3) * 8;
    const unsigned short* bg = Bt + (size_t)(bn + wave * 16 + (lane >> 2)) * ldb + (lane & 3) * 8;
    unsigned short* la = As + wave * 16 * 32;   // wave-uniform LDS bases
    unsigned short* lb = Bs + wave * 16 * 32;

    const short8* ap = (const short8*)(As + ((wr * 64 + (lane & 15)) * 32 + (lane >> 4) * 8));
    const short8* bp = (const short8*)(Bs + ((wc * 64 + (lane & 15)) * 32 + (lane >> 4) * 8));

    f32x4 acc[4][4] = {};

    const int nk = K >> 5;
    for (int kt = 0; kt < nk; ++kt) {
        GLD16(ag, la);
        GLD16(ag + (size_t)64 * lda, la + 64 * 32);
        GLD16(bg, lb);
        GLD16(bg + (size_t)64 * ldb, lb + 64 * 32);
        ag += 32; bg += 32;
        __syncthreads();
        short8 af[4], bfr[4];
        #pragma unroll
        for (int i = 0; i < 4; ++i) af[i] = ap[i * 64];
        #pragma unroll
        for (int i = 0; i < 4; ++i) bfr[i] = bp[i * 64];
        #pragma unroll
        for (int mi = 0; mi < 4; ++mi)
            #pragma unroll
            for (int ni = 0; ni < 4; ++ni)
                acc[mi][ni] = __builtin_amdgcn_mfma_f32_16x16x32_bf16(
                    af[mi], bfr[ni], acc[mi][ni], 0, 0, 0);
        __syncthreads();
    }

    const long cbase = (long)z * sC;
    #pragma unroll
    for (int mi = 0; mi < 4; ++mi) {
        #pragma unroll
        for (int ni = 0; ni < 4; ++ni) {
            #pragma unroll
            for (int r = 0; r < 4; ++r) {
                const int row = bm + wr * 64 + mi * 16 + (lane >> 4) * 4 + r;
                const int col = bn + wc * 64 + ni * 16 + (lane & 15);
                float v = acc[mi][ni][r];
                if (EPI == 0 || EPI == 3) v += bias[col];
                if (EPI == 1) {
                    v *= scale;
                    if (mask[(long)z * sM + (long)row * ldc + col] == 0)
                        v = -1e20f * scale;
                }
                if (EPI == 3)
                    ((float*)Cout)[cbase + (long)row * ldc + col] = v;
                else
                    ((unsigned short*)Cout)[cbase + (long)row * ldc + col] = f2bf(v);
            }
        }
    }
}

// ---------------------------------------------------------------------------
// Transpose+cast the four 1280x1280 f32 weights -> Wt[j][k] bf16
// ---------------------------------------------------------------------------
__global__ void transpose_w(const float* __restrict__ Wq, const float* __restrict__ Wk,
                            const float* __restrict__ Wv, const float* __restrict__ Wr,
                            unsigned short* __restrict__ Wt)
{
    const float* W = blockIdx.z == 0 ? Wq : blockIdx.z == 1 ? Wk : blockIdx.z == 2 ? Wv : Wr;
    unsigned short* dst = Wt + (size_t)blockIdx.z * 1280 * 1280;
    __shared__ float T[64][65];
    const int j0 = blockIdx.x * 64, k0 = blockIdx.y * 64;
    const int tid = threadIdx.x;
    for (int it = 0; it < 16; ++it) {
        int idx = it * 256 + tid;
        int r = idx >> 6, c = idx & 63;
        T[r][c] = W[(size_t)(k0 + r) * 1280 + j0 + c];
    }
    __syncthreads();
    for (int it = 0; it < 16; ++it) {
        int idx = it * 256 + tid;
        int r = idx >> 6, c = idx & 63;
        dst[(size_t)(j0 + r) * 1280 + k0 + c] = f2bf(T[c][r]);
    }
}

// ---------------------------------------------------------------------------
// Cast x f32 -> bf16, vectorized
// ---------------------------------------------------------------------------
__global__ void cast_x(const float* __restrict__ x, unsigned short* __restrict__ xb, long n)
{
    long i = ((long)blockIdx.x * 256 + threadIdx.x) * 8;
    if (i + 8 > n) return;
    const float4* p = (const float4*)(x + i);
    float4 a = p[0], b = p[1];
    unsigned short o[8] = { f2bf(a.x), f2bf(a.y), f2bf(a.z), f2bf(a.w),
                            f2bf(b.x), f2bf(b.y), f2bf(b.z), f2bf(b.w) };
    *(short8*)(xb + i) = *(short8*)o;
}

// ---------------------------------------------------------------------------
// Row softmax of scaled+masked scores S'[b][m][n] (bf16) and transposed write
// Pt[b][n][m] = softmax_row(S')[m][n].  One block per (64-row strip, batch).
// ---------------------------------------------------------------------------
#define SMS 514
__global__ void softmax_t(const unsigned short* __restrict__ S, unsigned short* __restrict__ Pt)
{
    __shared__ unsigned short T[64 * SMS];
    __shared__ float rmax[64], rinv[64];
    const int b = blockIdx.y, mb = blockIdx.x * 64;
    const int tid = threadIdx.x, lane = tid & 63, wave = tid >> 6;
    const unsigned short* src = S + ((size_t)b * 512 + mb) * 512;

    // load 64 rows x 512 cols; wave w handles rows w, w+4, ... (uint = 2 elems)
    for (int rr = 0; rr < 16; ++rr) {
        int r = rr * 4 + wave;
        const unsigned int* s = (const unsigned int*)(src + (size_t)r * 512);
        unsigned int* t = (unsigned int*)&T[r * SMS];
        #pragma unroll
        for (int j = 0; j < 4; ++j) t[lane + j * 64] = s[lane + j * 64];
    }
    __syncthreads();

    {   // row stats: 4 threads per row
        int r = tid >> 2, q = tid & 3;
        const unsigned short* row = &T[r * SMS + q * 128];
        float mx = -3.0e38f;
        for (int i = 0; i < 128; ++i) mx = fmaxf(mx, bf2f(row[i]));
        mx = fmaxf(mx, __shfl_xor(mx, 1));
        mx = fmaxf(mx, __shfl_xor(mx, 2));
        float s = 0.f;
        for (int i = 0; i < 128; ++i) s += expf(bf2f(row[i]) - mx);
        s += __shfl_xor(s, 1);
        s += __shfl_xor(s, 2);
        if (q == 0) { rmax[r] = mx; rinv[r] = 1.0f / s; }
    }
    __syncthreads();

    {   // transposed write: lane -> m, groups of 64 -> n
        int m = tid & 63, nq = tid >> 6;
        float mxm = rmax[m], rim = rinv[m];
        unsigned short* dst = Pt + (size_t)b * 512 * 512 + mb + m;
        for (int it = 0; it < 128; ++it) {
            int n = it * 4 + nq;
            float v = expf(bf2f(T[m * SMS + n]) - mxm) * rim;
            dst[(size_t)n * 512] = f2bf(v);
        }
    }
}

// ---------------------------------------------------------------------------
// Per-batch transpose V[b][m][c] -> Vt[b][c][m]  (bf16)
// ---------------------------------------------------------------------------
__global__ void transpose_v(const unsigned short* __restrict__ V, unsigned short* __restrict__ Vt)
{
    __shared__ unsigned short T[64][65];
    const int b = blockIdx.z;
    const int c0 = blockIdx.x * 64, m0 = blockIdx.y * 64;
    const int tid = threadIdx.x;
    const unsigned short* src = V + ((size_t)b * 512 + m0) * 1280 + c0;
    for (int it = 0; it < 16; ++it) {
        int idx = it * 256 + tid;
        int r = idx >> 6, c = idx & 63;
        T[r][c] = src[(size_t)r * 1280 + c];
    }
    __syncthreads();
    unsigned short* dst = Vt + ((size_t)b * 1280 + c0) * 512 + m0;
    for (int it = 0; it < 16; ++it) {
        int idx = it * 256 + tid;
        int r = idx >> 6, c = idx & 63;
        dst[(size_t)r * 512 + c] = T[c][r];
    }
}

// ---------------------------------------------------------------------------
extern "C" void kernel_launch(void* const* d_in, const int* in_sizes, int n_in,
                              void* d_out, int out_size, void* d_ws, size_t ws_size,
                              hipStream_t stream)
{
    const float* x   = (const float*)d_in[0];
    const int*  Mask = (const int*)d_in[1];
    const float* Wq  = (const float*)d_in[2];
    const float* bq  = (const float*)d_in[3];
    const float* Wk  = (const float*)d_in[4];
    const float* bk  = (const float*)d_in[5];
    const float* Wv  = (const float*)d_in[6];
    const float* bv  = (const float*)d_in[7];
    const float* Wr  = (const float*)d_in[8];
    const float* br  = (const float*)d_in[9];

    constexpr int B = 64, N = 512, C = 1280;
    constexpr long MN = (long)B * N;                 // 32768

    char* ws = (char*)d_ws;
    unsigned short* xb = (unsigned short*)ws;                         // MN*C bf16 (later: att)
    unsigned short* Wt = (unsigned short*)(ws + 83886080);            // 4*C*C bf16
    unsigned short* Q  = (unsigned short*)(ws + 83886080 + 13107200); // MN*C (later: Vt)
    unsigned short* Km = Q + 41943040;
    unsigned short* V  = Km + 41943040;
    unsigned short* Sp = V + 41943040;                                // B*N*N
    unsigned short* Pt = Sp + 16777216;                               // B*N*N
    unsigned short* Vt = Q;     // alias: Q dead after scores GEMM
    unsigned short* att = xb;   // alias: xb dead after QKV GEMMs

    const float scale = 0.02795084971874737f;   // 1/sqrt(1280)

    transpose_w<<<dim3(20, 20, 4), 256, 0, stream>>>(Wq, Wk, Wv, Wr, Wt);
    cast_x<<<dim3(20480), 256, 0, stream>>>(x, xb, MN * C);

    // QKV projections
    gemm_nt<0><<<dim3(256, 10, 1), 256, 0, stream>>>(xb, Wt,               (void*)Q,  bq, nullptr, C, C, C, C, 0, 0, 0, 0, 0.f);
    gemm_nt<0><<<dim3(256, 10, 1), 256, 0, stream>>>(xb, Wt + 1638400,     (void*)Km, bk, nullptr, C, C, C, C, 0, 0, 0, 0, 0.f);
    gemm_nt<0><<<dim3(256, 10, 1), 256, 0, stream>>>(xb, Wt + 2 * 1638400, (void*)V,  bv, nullptr, C, C, C, C, 0, 0, 0, 0, 0.f);

    // scores: S'[b][i][j] = scale * (Q[b][i] . K[b][j]), masked
    gemm_nt<1><<<dim3(4, 4, 64), 256, 0, stream>>>(Q, Km, (void*)Sp, nullptr, Mask,
        C, C, C, N, (long)N * C, (long)N * C, (long)N * N, (long)N * N, scale);

    // softmax rows + transposed store Pt[b][n][m]
    softmax_t<<<dim3(8, 64), 256, 0, stream>>>(Sp, Pt);

    // Vt[b][c][m]
    transpose_v<<<dim3(20, 8, 64), 256, 0, stream>>>(V, Vt);

    // att[b][n][c] = sum_m Pt[b][n][m] * Vt[b][c][m]
    gemm_nt<2><<<dim3(4, 10, 64), 256, 0, stream>>>(Pt, Vt, (void*)att, nullptr, nullptr,
        N, N, N, C, (long)N * N, (long)C * N, (long)N * C, 0, 0.f);

    // out = att @ Wr + br   (f32)
    gemm_nt<3><<<dim3(256, 10, 1), 256, 0, stream>>>(att, Wt + 3 * 1638400, d_out, br, nullptr,
        C, C, C, C, 0, 0, 0, 0, 0.f);
}

// Round 2
// 821.883 us; speedup vs baseline: 1.2708x; 1.2708x over previous
//
#include <hip/hip_runtime.h>
#include <hip/hip_bf16.h>

#define DI __device__ __forceinline__

typedef __attribute__((ext_vector_type(8))) short short8;
typedef __attribute__((ext_vector_type(4))) float f32x4;

DI unsigned short f2bf(float f) {
    union { float f; unsigned int u; } v; v.f = f;
    unsigned int r = v.u + 0x7FFFu + ((v.u >> 16) & 1u);
    return (unsigned short)(r >> 16);
}
DI float bf2f(unsigned short h) {
    union { unsigned int u; float f; } v; v.u = ((unsigned int)h) << 16;
    return v.f;
}

#define GLD16(g, l) __builtin_amdgcn_global_load_lds( \
    (const __attribute__((address_space(1))) void*)(g), \
    (__attribute__((address_space(3))) void*)(l), 16, 0, 0)

// ---------------------------------------------------------------------------
// 256x256 8-phase NT GEMM (T2+T3+T4+T5), BK=64, 8 waves (2M x 4N), 128KiB LDS.
// C[i][j] = sum_k A[i][k] * Bt[j][k]
// LDS: region(buf,h) = (buf*2+h)*16384 ushorts; A-half at +0 (256r x 32k),
// B-half at +8192. XOR swizzle: LDS[r][chunk] = G[r][chunk ^ (r&3)].
// EPI: 0 = +bias->bf16, 1 = *scale+mask->bf16, 2 = plain bf16, 3 = +bias->f32
// Requires: M%256==0, N%256==0, K%128==0, K>=256.
// ---------------------------------------------------------------------------
template<int EPI>
__global__ __launch_bounds__(512, 2) void gemm256(
    const unsigned short* __restrict__ A, const unsigned short* __restrict__ Bt,
    void* __restrict__ Cout, const float* __restrict__ bias,
    const int* __restrict__ mask, int K, int lda, int ldb, int ldc,
    long sA, long sB, long sC, long sM, float scale, int doswz)
{
    __shared__ unsigned short lds[65536];   // 128 KiB

    int bx = blockIdx.x;
    if (doswz) { const int c = gridDim.x >> 3; bx = (bx & 7) * c + (bx >> 3); }
    const int by = blockIdx.y, z = blockIdx.z;

    const int tid = threadIdx.x, wave = tid >> 6, l = tid & 63;
    const int wr = wave >> 2, wc = wave & 3;    // 2 x 4 wave grid

    const unsigned short* Ab = A + (long)z * sA + (size_t)(bx * 256) * lda;
    const unsigned short* Bb = Bt + (long)z * sB + (size_t)(by * 256) * ldb;

    // staging: wave covers rows [wave*32, wave*32+32); lane l -> row +(l>>2),
    // source chunk pre-swizzled so LDS[r][c] = G[r][c ^ (r&3)]
    const int srow = wave * 32 + (l >> 2);
    const int schunk = ((l & 3) ^ ((l >> 2) & 3)) * 8;
    const unsigned short* agS = Ab + (size_t)srow * lda + schunk;
    const unsigned short* bgS = Bb + (size_t)srow * ldb + schunk;
    unsigned short* ldsA0 = &lds[wave * 1024];
    unsigned short* ldsB0 = &lds[8192 + wave * 1024];

    // ds_read offsets (ushort units); row stride 32, chunk = (l>>4)^(l&3)
    const int rl = l & 15;
    const int cl8 = ((l >> 4) ^ (l & 3)) * 8;
    const int aoff = (wr * 128 + rl) * 32 + cl8;
    const int boff = 8192 + (wc * 64 + rl) * 32 + cl8;

#define REGOFF(buf, h) (((buf) * 2 + (h)) * 16384)
#define SA(t, h, buf) { const unsigned short* g_ = agS + (size_t)((t) * 64 + (h) * 32); \
    GLD16(g_, ldsA0 + REGOFF(buf, h)); \
    GLD16(g_ + (size_t)16 * lda, ldsA0 + REGOFF(buf, h) + 512); }
#define SB(t, h, buf) { const unsigned short* g_ = bgS + (size_t)((t) * 64 + (h) * 32); \
    GLD16(g_, ldsB0 + REGOFF(buf, h)); \
    GLD16(g_ + (size_t)16 * ldb, ldsB0 + REGOFF(buf, h) + 512); }

    f32x4 acc[8][4] = {};
    short8 bfr[4];

#define PHASE(mg, h, buf, RDB, STG, VMW) { \
    short8 af[4]; \
    if (RDB) { \
        _Pragma("unroll") for (int n = 0; n < 4; ++n) \
            bfr[n] = *(const short8*)&lds[REGOFF(buf, h) + boff + n * 512]; \
    } \
    _Pragma("unroll") for (int i = 0; i < 4; ++i) \
        af[i] = *(const short8*)&lds[REGOFF(buf, h) + aoff + ((mg) * 4 + i) * 512]; \
    STG; \
    __builtin_amdgcn_s_barrier(); \
    asm volatile("s_waitcnt lgkmcnt(0)" ::: "memory"); \
    __builtin_amdgcn_sched_barrier(0); \
    __builtin_amdgcn_s_setprio(1); \
    _Pragma("unroll") for (int i = 0; i < 4; ++i) \
        _Pragma("unroll") for (int n = 0; n < 4; ++n) \
            acc[(mg) * 4 + i][n] = __builtin_amdgcn_mfma_f32_16x16x32_bf16( \
                af[i], bfr[n], acc[(mg) * 4 + i][n], 0, 0, 0); \
    __builtin_amdgcn_s_setprio(0); \
    asm volatile("s_waitcnt " VMW ::: "memory"); \
    __builtin_amdgcn_s_barrier(); \
  }

    // prologue: tile0 full + tile1 k0  (12 loads); drain tile0.k0 (oldest 4)
    SA(0, 0, 0); SB(0, 0, 0); SA(0, 1, 0); SB(0, 1, 0); SA(1, 0, 1); SB(1, 0, 1);
    asm volatile("s_waitcnt vmcnt(8)" ::: "memory");
    __builtin_amdgcn_s_barrier();

    const int NI = K >> 7;          // iterations, 2 K-tiles (BK=64) each
    for (int j = 0; j < NI - 1; ++j) {
        const int t = 2 * j;
        PHASE(0, 0, 0, 1, SA(t + 1, 1, 1), "vmcnt(8)")
        PHASE(1, 0, 0, 0, SB(t + 1, 1, 1), "vmcnt(8)")
        PHASE(0, 1, 0, 1, SA(t + 2, 0, 0), "vmcnt(8)")
        PHASE(1, 1, 0, 0, SB(t + 2, 0, 0), "vmcnt(8)")
        PHASE(0, 0, 1, 1, SA(t + 2, 1, 0), "vmcnt(8)")
        PHASE(1, 0, 1, 0, SB(t + 2, 1, 0), "vmcnt(8)")
        PHASE(0, 1, 1, 1, SA(t + 3, 0, 1), "vmcnt(8)")
        PHASE(1, 1, 1, 0, SB(t + 3, 0, 1), "vmcnt(8)")
    }
    {   // peeled last iteration: stage only tile NT-1 k1; drain 8 -> 4 -> 0
        const int t = 2 * (NI - 1);
        PHASE(0, 0, 0, 1, SA(t + 1, 1, 1), "vmcnt(8)")
        PHASE(1, 0, 0, 0, SB(t + 1, 1, 1), "vmcnt(8)")
        PHASE(0, 1, 0, 1, ((void)0),       "vmcnt(8)")
        PHASE(1, 1, 0, 0, ((void)0),       "vmcnt(4)")
        PHASE(0, 0, 1, 1, ((void)0),       "vmcnt(4)")
        PHASE(1, 0, 1, 0, ((void)0),       "vmcnt(0)")
        PHASE(0, 1, 1, 1, ((void)0),       "vmcnt(0)")
        PHASE(1, 1, 1, 0, ((void)0),       "vmcnt(0)")
    }
#undef PHASE
#undef SA
#undef SB
#undef REGOFF

    // epilogue
    const long cb = (long)z * sC;
    const int row0 = bx * 256 + wr * 128 + (l >> 4) * 4;
    const int col0 = by * 256 + wc * 64 + rl;
    #pragma unroll
    for (int mi = 0; mi < 8; ++mi) {
        #pragma unroll
        for (int n = 0; n < 4; ++n) {
            #pragma unroll
            for (int r = 0; r < 4; ++r) {
                const int row = row0 + mi * 16 + r;
                const int col = col0 + n * 16;
                float v = acc[mi][n][r];
                if (EPI == 0 || EPI == 3) v += bias[col];
                if (EPI == 1) {
                    v *= scale;
                    if (mask[(long)z * sM + (long)row * ldc + col] == 0)
                        v = -1e20f * scale;
                }
                if (EPI == 3)
                    ((float*)Cout)[cb + (long)row * ldc + col] = v;
                else
                    ((unsigned short*)Cout)[cb + (long)row * ldc + col] = f2bf(v);
            }
        }
    }
}

// ---------------------------------------------------------------------------
// Transpose+cast the four 1280x1280 f32 weights -> Wt[j][k] bf16
// ---------------------------------------------------------------------------
__global__ void transpose_w(const float* __restrict__ Wq, const float* __restrict__ Wk,
                            const float* __restrict__ Wv, const float* __restrict__ Wr,
                            unsigned short* __restrict__ Wt)
{
    const float* W = blockIdx.z == 0 ? Wq : blockIdx.z == 1 ? Wk : blockIdx.z == 2 ? Wv : Wr;
    unsigned short* dst = Wt + (size_t)blockIdx.z * 1280 * 1280;
    __shared__ float T[64][65];
    const int j0 = blockIdx.x * 64, k0 = blockIdx.y * 64;
    const int tid = threadIdx.x;
    for (int it = 0; it < 16; ++it) {
        int idx = it * 256 + tid;
        int r = idx >> 6, c = idx & 63;
        T[r][c] = W[(size_t)(k0 + r) * 1280 + j0 + c];
    }
    __syncthreads();
    for (int it = 0; it < 16; ++it) {
        int idx = it * 256 + tid;
        int r = idx >> 6, c = idx & 63;
        dst[(size_t)(j0 + r) * 1280 + k0 + c] = f2bf(T[c][r]);
    }
}

// ---------------------------------------------------------------------------
// Cast x f32 -> bf16, vectorized
// ---------------------------------------------------------------------------
__global__ void cast_x(const float* __restrict__ x, unsigned short* __restrict__ xb, long n)
{
    long i = ((long)blockIdx.x * 256 + threadIdx.x) * 8;
    if (i + 8 > n) return;
    const float4* p = (const float4*)(x + i);
    float4 a = p[0], b = p[1];
    unsigned short o[8] = { f2bf(a.x), f2bf(a.y), f2bf(a.z), f2bf(a.w),
                            f2bf(b.x), f2bf(b.y), f2bf(b.z), f2bf(b.w) };
    *(short8*)(xb + i) = *(short8*)o;
}

// ---------------------------------------------------------------------------
// Row softmax of scaled+masked scores S'[b][m][n] (bf16) and transposed write
// Pt[b][n][m] = softmax_row(S')[m][n].  One block per (64-row strip, batch).
// ---------------------------------------------------------------------------
#define SMS 514
__global__ void softmax_t(const unsigned short* __restrict__ S, unsigned short* __restrict__ Pt)
{
    __shared__ unsigned short T[64 * SMS];
    __shared__ float rmax[64], rinv[64];
    const int b = blockIdx.y, mb = blockIdx.x * 64;
    const int tid = threadIdx.x, lane = tid & 63, wave = tid >> 6;
    const unsigned short* src = S + ((size_t)b * 512 + mb) * 512;

    for (int rr = 0; rr < 16; ++rr) {
        int r = rr * 4 + wave;
        const unsigned int* s = (const unsigned int*)(src + (size_t)r * 512);
        unsigned int* t = (unsigned int*)&T[r * SMS];
        #pragma unroll
        for (int j = 0; j < 4; ++j) t[lane + j * 64] = s[lane + j * 64];
    }
    __syncthreads();

    {   // row stats: 4 threads per row
        int r = tid >> 2, q = tid & 3;
        const unsigned short* row = &T[r * SMS + q * 128];
        float mx = -3.0e38f;
        for (int i = 0; i < 128; ++i) mx = fmaxf(mx, bf2f(row[i]));
        mx = fmaxf(mx, __shfl_xor(mx, 1));
        mx = fmaxf(mx, __shfl_xor(mx, 2));
        float s = 0.f;
        for (int i = 0; i < 128; ++i) s += expf(bf2f(row[i]) - mx);
        s += __shfl_xor(s, 1);
        s += __shfl_xor(s, 2);
        if (q == 0) { rmax[r] = mx; rinv[r] = 1.0f / s; }
    }
    __syncthreads();

    {   // transposed write: lane -> m, groups of 64 -> n
        int m = tid & 63, nq = tid >> 6;
        float mxm = rmax[m], rim = rinv[m];
        unsigned short* dst = Pt + (size_t)b * 512 * 512 + mb + m;
        for (int it = 0; it < 128; ++it) {
            int n = it * 4 + nq;
            float v = expf(bf2f(T[m * SMS + n]) - mxm) * rim;
            dst[(size_t)n * 512] = f2bf(v);
        }
    }
}

// ---------------------------------------------------------------------------
// Per-batch transpose V[b][m][c] -> Vt[b][c][m]  (bf16)
// ---------------------------------------------------------------------------
__global__ void transpose_v(const unsigned short* __restrict__ V, unsigned short* __restrict__ Vt)
{
    __shared__ unsigned short T[64][65];
    const int b = blockIdx.z;
    const int c0 = blockIdx.x * 64, m0 = blockIdx.y * 64;
    const int tid = threadIdx.x;
    const unsigned short* src = V + ((size_t)b * 512 + m0) * 1280 + c0;
    for (int it = 0; it < 16; ++it) {
        int idx = it * 256 + tid;
        int r = idx >> 6, c = idx & 63;
        T[r][c] = src[(size_t)r * 1280 + c];
    }
    __syncthreads();
    unsigned short* dst = Vt + ((size_t)b * 1280 + c0) * 512 + m0;
    for (int it = 0; it < 16; ++it) {
        int idx = it * 256 + tid;
        int r = idx >> 6, c = idx & 63;
        dst[(size_t)r * 512 + c] = T[c][r];
    }
}

// ---------------------------------------------------------------------------
extern "C" void kernel_launch(void* const* d_in, const int* in_sizes, int n_in,
                              void* d_out, int out_size, void* d_ws, size_t ws_size,
                              hipStream_t stream)
{
    const float* x   = (const float*)d_in[0];
    const int*  Mask = (const int*)d_in[1];
    const float* Wq  = (const float*)d_in[2];
    const float* bq  = (const float*)d_in[3];
    const float* Wk  = (const float*)d_in[4];
    const float* bk  = (const float*)d_in[5];
    const float* Wv  = (const float*)d_in[6];
    const float* bv  = (const float*)d_in[7];
    const float* Wr  = (const float*)d_in[8];
    const float* br  = (const float*)d_in[9];

    constexpr int N = 512, C = 1280;
    constexpr long MN = 32768;   // B*N

    char* ws = (char*)d_ws;
    unsigned short* xb = (unsigned short*)ws;                         // MN*C bf16 (later: att)
    unsigned short* Wt = (unsigned short*)(ws + 83886080);            // 4*C*C bf16
    unsigned short* Q  = (unsigned short*)(ws + 83886080 + 13107200); // MN*C (later: Vt)
    unsigned short* Km = Q + 41943040;
    unsigned short* V  = Km + 41943040;
    unsigned short* Sp = V + 41943040;                                // B*N*N
    unsigned short* Pt = Sp + 16777216;                               // B*N*N
    unsigned short* Vt = Q;     // alias: Q dead after scores GEMM
    unsigned short* att = xb;   // alias: xb dead after QKV GEMMs

    const float scale = 0.02795084971874737f;   // 1/sqrt(1280)

    transpose_w<<<dim3(20, 20, 4), 256, 0, stream>>>(Wq, Wk, Wv, Wr, Wt);
    cast_x<<<dim3(20480), 256, 0, stream>>>(x, xb, MN * C);

    // QKV projections: M=32768, N=1280, K=1280
    gemm256<0><<<dim3(128, 5, 1), 512, 0, stream>>>(xb, Wt,               (void*)Q,  bq, nullptr, C, C, C, C, 0, 0, 0, 0, 0.f, 1);
    gemm256<0><<<dim3(128, 5, 1), 512, 0, stream>>>(xb, Wt + 1638400,     (void*)Km, bk, nullptr, C, C, C, C, 0, 0, 0, 0, 0.f, 1);
    gemm256<0><<<dim3(128, 5, 1), 512, 0, stream>>>(xb, Wt + 2 * 1638400, (void*)V,  bv, nullptr, C, C, C, C, 0, 0, 0, 0, 0.f, 1);

    // scores: S'[b][i][j] = scale * (Q[b][i] . K[b][j]), masked
    gemm256<1><<<dim3(2, 2, 64), 512, 0, stream>>>(Q, Km, (void*)Sp, nullptr, Mask,
        C, C, C, N, (long)N * C, (long)N * C, (long)N * N, (long)N * N, scale, 0);

    // softmax rows + transposed store Pt[b][n][m]
    softmax_t<<<dim3(8, 64), 256, 0, stream>>>(Sp, Pt);

    // Vt[b][c][m]
    transpose_v<<<dim3(20, 8, 64), 256, 0, stream>>>(V, Vt);

    // att[b][n][c] = sum_m Pt[b][n][m] * Vt[b][c][m]   (M=512, N=1280, K=512)
    gemm256<2><<<dim3(2, 5, 64), 512, 0, stream>>>(Pt, Vt, (void*)att, nullptr, nullptr,
        N, N, N, C, (long)N * N, (long)C * N, (long)N * C, 0, 0.f, 0);

    // out = att @ Wr + br   (f32)
    gemm256<3><<<dim3(128, 5, 1), 512, 0, stream>>>(att, Wt + 3 * 1638400, d_out, br, nullptr,
        C, C, C, C, 0, 0, 0, 0, 0.f, 1);
}

// Round 3
// 782.022 us; speedup vs baseline: 1.3356x; 1.0510x over previous
//
#include <hip/hip_runtime.h>
#include <hip/hip_bf16.h>

#define DI __device__ __forceinline__

typedef __attribute__((ext_vector_type(8))) short short8;
typedef __attribute__((ext_vector_type(4))) float f32x4;

DI unsigned short f2bf(float f) {
    union { float f; unsigned int u; } v; v.f = f;
    unsigned int r = v.u + 0x7FFFu + ((v.u >> 16) & 1u);
    return (unsigned short)(r >> 16);
}
DI float bf2f(unsigned short h) {
    union { unsigned int u; float f; } v; v.u = ((unsigned int)h) << 16;
    return v.f;
}

#define GLD16(g, l) __builtin_amdgcn_global_load_lds( \
    (const __attribute__((address_space(1))) void*)(g), \
    (__attribute__((address_space(3))) void*)(l), 16, 0, 0)

// ---------------------------------------------------------------------------
// 256x256 8-phase NT GEMM (T2+T3+T4+T5), BK=64, 8 waves (2M x 4N), 128KiB LDS.
// C[i][j] = sum_k A[i][k] * Bt[j][k]
// LDS swizzle: LDS[r][p] = G[r][p ^ ((r>>1)&3)]  (bank period is 2 rows:
// row r -> banks 16r mod 32; XOR with row bits [2:1] makes each 8-lane
// b128 quarter-group cover all 32 banks).
// EPI: 0 = +bias->bf16, 1 = *scale+mask->bf16, 2 = plain bf16, 3 = +bias->f32
// QKV=1: by in [0,15); group g=by/5 selects Bt/Cout/bias via sB/sC strides.
// Requires: M%256==0, N%256==0, K%128==0, K>=256.
// ---------------------------------------------------------------------------
template<int EPI, int QKV>
__global__ __launch_bounds__(512, 2) void gemm256(
    const unsigned short* __restrict__ A, const unsigned short* __restrict__ Bt,
    void* __restrict__ Cout, const float* __restrict__ bias,
    const float* __restrict__ bias1, const float* __restrict__ bias2,
    const int* __restrict__ mask, int K, int lda, int ldb, int ldc,
    long sA, long sB, long sC, long sM, float scale, int doswz)
{
    __shared__ unsigned short lds[65536];   // 128 KiB

    int bx = blockIdx.x;
    if (doswz) { const int c = gridDim.x >> 3; bx = (bx & 7) * c + (bx >> 3); }
    int by = blockIdx.y;
    const int z = blockIdx.z;

    if (QKV) {
        const int g = by / 5; by -= g * 5;
        Bt += (size_t)g * sB;
        Cout = (void*)((unsigned short*)Cout + (size_t)g * sC);
        if (g == 1) bias = bias1; else if (g == 2) bias = bias2;
    }

    const unsigned short* Ab = A + (long)z * sA + (size_t)(bx * 256) * lda;
    const unsigned short* Bb = Bt + (QKV ? 0 : (long)z * sB) + (size_t)(by * 256) * ldb;

    const int tid = threadIdx.x, wave = tid >> 6, l = tid & 63;
    const int wr = wave >> 2, wc = wave & 3;    // 2 x 4 wave grid

    // staging: wave covers rows [wave*32, wave*32+32); lane l -> row +(l>>2);
    // source chunk pre-swizzled: LDS[r][p] = G[r][p ^ ((r>>1)&3)], row per
    // lane = l>>2 so (row>>1)&3 = (l>>3)&3
    const int srow = wave * 32 + (l >> 2);
    const int schunk = ((l & 3) ^ ((l >> 3) & 3)) * 8;
    const unsigned short* agS = Ab + (size_t)srow * lda + schunk;
    const unsigned short* bgS = Bb + (size_t)srow * ldb + schunk;
    unsigned short* ldsA0 = &lds[wave * 1024];
    unsigned short* ldsB0 = &lds[8192 + wave * 1024];

    // ds_read offsets (ushort units); row = l&15 (+multiples of 16), so
    // (row>>1)&3 = (l>>1)&3; phys chunk = kchunk(l>>4) ^ ((l>>1)&3)
    const int rl = l & 15;
    const int cl8 = ((l >> 4) ^ ((l >> 1) & 3)) * 8;
    const int aoff = (wr * 128 + rl) * 32 + cl8;
    const int boff = 8192 + (wc * 64 + rl) * 32 + cl8;

#define REGOFF(buf, h) (((buf) * 2 + (h)) * 16384)
#define SA(t, h, buf) { const unsigned short* g_ = agS + (size_t)((t) * 64 + (h) * 32); \
    GLD16(g_, ldsA0 + REGOFF(buf, h)); \
    GLD16(g_ + (size_t)16 * lda, ldsA0 + REGOFF(buf, h) + 512); }
#define SB(t, h, buf) { const unsigned short* g_ = bgS + (size_t)((t) * 64 + (h) * 32); \
    GLD16(g_, ldsB0 + REGOFF(buf, h)); \
    GLD16(g_ + (size_t)16 * ldb, ldsB0 + REGOFF(buf, h) + 512); }

    f32x4 acc[8][4] = {};
    short8 bfr[4];

#define PHASE(mg, h, buf, RDB, STG, VMW) { \
    short8 af[4]; \
    if (RDB) { \
        _Pragma("unroll") for (int n = 0; n < 4; ++n) \
            bfr[n] = *(const short8*)&lds[REGOFF(buf, h) + boff + n * 512]; \
    } \
    _Pragma("unroll") for (int i = 0; i < 4; ++i) \
        af[i] = *(const short8*)&lds[REGOFF(buf, h) + aoff + ((mg) * 4 + i) * 512]; \
    STG; \
    __builtin_amdgcn_s_barrier(); \
    asm volatile("s_waitcnt lgkmcnt(0)" ::: "memory"); \
    __builtin_amdgcn_sched_barrier(0); \
    __builtin_amdgcn_s_setprio(1); \
    _Pragma("unroll") for (int i = 0; i < 4; ++i) \
        _Pragma("unroll") for (int n = 0; n < 4; ++n) \
            acc[(mg) * 4 + i][n] = __builtin_amdgcn_mfma_f32_16x16x32_bf16( \
                af[i], bfr[n], acc[(mg) * 4 + i][n], 0, 0, 0); \
    __builtin_amdgcn_s_setprio(0); \
    asm volatile("s_waitcnt " VMW ::: "memory"); \
    __builtin_amdgcn_s_barrier(); \
  }

    // prologue: tile0 full + tile1 k0  (12 loads); drain tile0.k0 (oldest 4)
    SA(0, 0, 0); SB(0, 0, 0); SA(0, 1, 0); SB(0, 1, 0); SA(1, 0, 1); SB(1, 0, 1);
    asm volatile("s_waitcnt vmcnt(8)" ::: "memory");
    __builtin_amdgcn_s_barrier();

    const int NI = K >> 7;          // iterations, 2 K-tiles (BK=64) each
    for (int j = 0; j < NI - 1; ++j) {
        const int t = 2 * j;
        PHASE(0, 0, 0, 1, SA(t + 1, 1, 1), "vmcnt(8)")
        PHASE(1, 0, 0, 0, SB(t + 1, 1, 1), "vmcnt(8)")
        PHASE(0, 1, 0, 1, SA(t + 2, 0, 0), "vmcnt(8)")
        PHASE(1, 1, 0, 0, SB(t + 2, 0, 0), "vmcnt(8)")
        PHASE(0, 0, 1, 1, SA(t + 2, 1, 0), "vmcnt(8)")
        PHASE(1, 0, 1, 0, SB(t + 2, 1, 0), "vmcnt(8)")
        PHASE(0, 1, 1, 1, SA(t + 3, 0, 1), "vmcnt(8)")
        PHASE(1, 1, 1, 0, SB(t + 3, 0, 1), "vmcnt(8)")
    }
    {   // peeled last iteration: stage only tile NT-1 k1; drain 8 -> 4 -> 0
        const int t = 2 * (NI - 1);
        PHASE(0, 0, 0, 1, SA(t + 1, 1, 1), "vmcnt(8)")
        PHASE(1, 0, 0, 0, SB(t + 1, 1, 1), "vmcnt(8)")
        PHASE(0, 1, 0, 1, ((void)0),       "vmcnt(8)")
        PHASE(1, 1, 0, 0, ((void)0),       "vmcnt(4)")
        PHASE(0, 0, 1, 1, ((void)0),       "vmcnt(4)")
        PHASE(1, 0, 1, 0, ((void)0),       "vmcnt(0)")
        PHASE(0, 1, 1, 1, ((void)0),       "vmcnt(0)")
        PHASE(1, 1, 1, 0, ((void)0),       "vmcnt(0)")
    }
#undef PHASE
#undef SA
#undef SB
#undef REGOFF

    // epilogue
    const long cb = QKV ? 0 : (long)z * sC;
    const int row0 = bx * 256 + wr * 128 + (l >> 4) * 4;
    const int col0 = by * 256 + wc * 64 + rl;
    #pragma unroll
    for (int mi = 0; mi < 8; ++mi) {
        #pragma unroll
        for (int n = 0; n < 4; ++n) {
            #pragma unroll
            for (int r = 0; r < 4; ++r) {
                const int row = row0 + mi * 16 + r;
                const int col = col0 + n * 16;
                float v = acc[mi][n][r];
                if (EPI == 0 || EPI == 3) v += bias[col];
                if (EPI == 1) {
                    v *= scale;
                    if (mask[(long)z * sM + (long)row * ldc + col] == 0)
                        v = -1e20f * scale;
                }
                if (EPI == 3)
                    ((float*)Cout)[cb + (long)row * ldc + col] = v;
                else
                    ((unsigned short*)Cout)[cb + (long)row * ldc + col] = f2bf(v);
            }
        }
    }
}

// ---------------------------------------------------------------------------
// Transpose+cast the four 1280x1280 f32 weights -> Wt[j][k] bf16
// ---------------------------------------------------------------------------
__global__ void transpose_w(const float* __restrict__ Wq, const float* __restrict__ Wk,
                            const float* __restrict__ Wv, const float* __restrict__ Wr,
                            unsigned short* __restrict__ Wt)
{
    const float* W = blockIdx.z == 0 ? Wq : blockIdx.z == 1 ? Wk : blockIdx.z == 2 ? Wv : Wr;
    unsigned short* dst = Wt + (size_t)blockIdx.z * 1280 * 1280;
    __shared__ float T[64][65];
    const int j0 = blockIdx.x * 64, k0 = blockIdx.y * 64;
    const int tid = threadIdx.x;
    for (int it = 0; it < 16; ++it) {
        int idx = it * 256 + tid;
        int r = idx >> 6, c = idx & 63;
        T[r][c] = W[(size_t)(k0 + r) * 1280 + j0 + c];
    }
    __syncthreads();
    for (int it = 0; it < 16; ++it) {
        int idx = it * 256 + tid;
        int r = idx >> 6, c = idx & 63;
        dst[(size_t)(j0 + r) * 1280 + k0 + c] = f2bf(T[c][r]);
    }
}

// ---------------------------------------------------------------------------
// Cast x f32 -> bf16, vectorized
// ---------------------------------------------------------------------------
__global__ void cast_x(const float* __restrict__ x, unsigned short* __restrict__ xb, long n)
{
    long i = ((long)blockIdx.x * 256 + threadIdx.x) * 8;
    if (i + 8 > n) return;
    const float4* p = (const float4*)(x + i);
    float4 a = p[0], b = p[1];
    unsigned short o[8] = { f2bf(a.x), f2bf(a.y), f2bf(a.z), f2bf(a.w),
                            f2bf(b.x), f2bf(b.y), f2bf(b.z), f2bf(b.w) };
    *(short8*)(xb + i) = *(short8*)o;
}

// ---------------------------------------------------------------------------
// Row softmax of scaled+masked scores S'[b][m][n] (bf16) and transposed write
// Pt[b][n][m] = softmax_row(S')[m][n].  One block per (64-row strip, batch).
// ---------------------------------------------------------------------------
#define SMS 514
__global__ void softmax_t(const unsigned short* __restrict__ S, unsigned short* __restrict__ Pt)
{
    __shared__ unsigned short T[64 * SMS];
    __shared__ float rmax[64], rinv[64];
    const int b = blockIdx.y, mb = blockIdx.x * 64;
    const int tid = threadIdx.x, lane = tid & 63, wave = tid >> 6;
    const unsigned short* src = S + ((size_t)b * 512 + mb) * 512;

    for (int rr = 0; rr < 16; ++rr) {
        int r = rr * 4 + wave;
        const unsigned int* s = (const unsigned int*)(src + (size_t)r * 512);
        unsigned int* t = (unsigned int*)&T[r * SMS];
        #pragma unroll
        for (int j = 0; j < 4; ++j) t[lane + j * 64] = s[lane + j * 64];
    }
    __syncthreads();

    {   // row stats: 4 threads per row
        int r = tid >> 2, q = tid & 3;
        const unsigned short* row = &T[r * SMS + q * 128];
        float mx = -3.0e38f;
        for (int i = 0; i < 128; ++i) mx = fmaxf(mx, bf2f(row[i]));
        mx = fmaxf(mx, __shfl_xor(mx, 1));
        mx = fmaxf(mx, __shfl_xor(mx, 2));
        float s = 0.f;
        for (int i = 0; i < 128; ++i) s += expf(bf2f(row[i]) - mx);
        s += __shfl_xor(s, 1);
        s += __shfl_xor(s, 2);
        if (q == 0) { rmax[r] = mx; rinv[r] = 1.0f / s; }
    }
    __syncthreads();

    {   // transposed write: lane -> m, groups of 64 -> n
        int m = tid & 63, nq = tid >> 6;
        float mxm = rmax[m], rim = rinv[m];
        unsigned short* dst = Pt + (size_t)b * 512 * 512 + mb + m;
        for (int it = 0; it < 128; ++it) {
            int n = it * 4 + nq;
            float v = expf(bf2f(T[m * SMS + n]) - mxm) * rim;
            dst[(size_t)n * 512] = f2bf(v);
        }
    }
}

// ---------------------------------------------------------------------------
// Per-batch transpose V[b][m][c] -> Vt[b][c][m]  (bf16)
// ---------------------------------------------------------------------------
__global__ void transpose_v(const unsigned short* __restrict__ V, unsigned short* __restrict__ Vt)
{
    __shared__ unsigned short T[64][65];
    const int b = blockIdx.z;
    const int c0 = blockIdx.x * 64, m0 = blockIdx.y * 64;
    const int tid = threadIdx.x;
    const unsigned short* src = V + ((size_t)b * 512 + m0) * 1280 + c0;
    for (int it = 0; it < 16; ++it) {
        int idx = it * 256 + tid;
        int r = idx >> 6, c = idx & 63;
        T[r][c] = src[(size_t)r * 1280 + c];
    }
    __syncthreads();
    unsigned short* dst = Vt + ((size_t)b * 1280 + c0) * 512 + m0;
    for (int it = 0; it < 16; ++it) {
        int idx = it * 256 + tid;
        int r = idx >> 6, c = idx & 63;
        dst[(size_t)r * 512 + c] = T[c][r];
    }
}

// ---------------------------------------------------------------------------
extern "C" void kernel_launch(void* const* d_in, const int* in_sizes, int n_in,
                              void* d_out, int out_size, void* d_ws, size_t ws_size,
                              hipStream_t stream)
{
    const float* x   = (const float*)d_in[0];
    const int*  Mask = (const int*)d_in[1];
    const float* Wq  = (const float*)d_in[2];
    const float* bq  = (const float*)d_in[3];
    const float* Wk  = (const float*)d_in[4];
    const float* bk  = (const float*)d_in[5];
    const float* Wv  = (const float*)d_in[6];
    const float* bv  = (const float*)d_in[7];
    const float* Wr  = (const float*)d_in[8];
    const float* br  = (const float*)d_in[9];

    constexpr int N = 512, C = 1280;
    constexpr long MN = 32768;   // B*N

    char* ws = (char*)d_ws;
    unsigned short* xb = (unsigned short*)ws;                         // MN*C bf16 (later: att)
    unsigned short* Wt = (unsigned short*)(ws + 83886080);            // 4*C*C bf16
    unsigned short* Q  = (unsigned short*)(ws + 83886080 + 13107200); // MN*C (later: Vt)
    unsigned short* Km = Q + 41943040;
    unsigned short* V  = Km + 41943040;
    unsigned short* Sp = V + 41943040;                                // B*N*N
    unsigned short* Pt = Sp + 16777216;                               // B*N*N
    unsigned short* Vt = Q;     // alias: Q dead after scores GEMM
    unsigned short* att = xb;   // alias: xb dead after QKV GEMMs

    const float scale = 0.02795084971874737f;   // 1/sqrt(1280)

    transpose_w<<<dim3(20, 20, 4), 256, 0, stream>>>(Wq, Wk, Wv, Wr, Wt);
    cast_x<<<dim3(20480), 256, 0, stream>>>(x, xb, MN * C);

    // fused QKV projections: M=32768, N=3x1280, K=1280; by/5 selects group
    gemm256<0, 1><<<dim3(128, 15, 1), 512, 0, stream>>>(xb, Wt, (void*)Q, bq, bk, bv,
        nullptr, C, C, C, C, 0, 1638400L, 41943040L, 0, 0.f, 1);

    // scores: S'[b][i][j] = scale * (Q[b][i] . K[b][j]), masked
    gemm256<1, 0><<<dim3(2, 2, 64), 512, 0, stream>>>(Q, Km, (void*)Sp, nullptr, nullptr, nullptr,
        Mask, C, C, C, N, (long)N * C, (long)N * C, (long)N * N, (long)N * N, scale, 0);

    // softmax rows + transposed store Pt[b][n][m]
    softmax_t<<<dim3(8, 64), 256, 0, stream>>>(Sp, Pt);

    // Vt[b][c][m]
    transpose_v<<<dim3(20, 8, 64), 256, 0, stream>>>(V, Vt);

    // att[b][n][c] = sum_m Pt[b][n][m] * Vt[b][c][m]   (M=512, N=1280, K=512)
    gemm256<2, 0><<<dim3(2, 5, 64), 512, 0, stream>>>(Pt, Vt, (void*)att, nullptr, nullptr, nullptr,
        nullptr, N, N, N, C, (long)N * N, (long)C * N, (long)N * C, 0, 0.f, 0);

    // out = att @ Wr + br   (f32)
    gemm256<3, 0><<<dim3(128, 5, 1), 512, 0, stream>>>(att, Wt + 3 * 1638400, d_out, br, nullptr, nullptr,
        nullptr, C, C, C, C, 0, 0, 0, 0, 0.f, 1);
}

// Round 4
// 781.415 us; speedup vs baseline: 1.3366x; 1.0008x over previous
//
#include <hip/hip_runtime.h>
#include <hip/hip_bf16.h>

#define DI __device__ __forceinline__

typedef __attribute__((ext_vector_type(8))) short short8;
typedef __attribute__((ext_vector_type(4))) float f32x4;

DI unsigned short f2bf(float f) {
    union { float f; unsigned int u; } v; v.f = f;
    unsigned int r = v.u + 0x7FFFu + ((v.u >> 16) & 1u);
    return (unsigned short)(r >> 16);
}
DI float bf2f(unsigned short h) {
    union { unsigned int u; float f; } v; v.u = ((unsigned int)h) << 16;
    return v.f;
}

#define GLD16(g, l) __builtin_amdgcn_global_load_lds( \
    (const __attribute__((address_space(1))) void*)(g), \
    (__attribute__((address_space(3))) void*)(l), 16, 0, 0)

// ---------------------------------------------------------------------------
// 256x128 NT GEMM, 256 threads (4 waves, 2Mx2N; per-wave 128x64), rotation-3
// K-region pipeline (region = 32 k-cols: A 256x32 + B 128x32 = 24KB), 72KB LDS
// -> 2 blocks/CU.  C[i][j] = sum_k A[i][k]*Bt[j][k].
// Swizzle: LDS[r][p] = G[r][p ^ ((r>>1)&3)] (bank-period-2 rows; verified
// conflict-free in r3).  Counted vmcnt(6) once per K-tile, never 0 in loop.
// Grid: x = N-tile (fast, locality), y = M-tile, z = batch.
// EPI: 0 = +bias->bf16, 1 = *scale+mask->bf16, 2 = plain bf16, 3 = +bias->f32
// QKV=1: x in [0,30); g = x/10 selects Bt/Cout/bias.
// Requires: M%256==0, N%128==0, K%32==0, K>=64.
// ---------------------------------------------------------------------------
template<int EPI, int QKV>
__global__ __launch_bounds__(256, 2) void gemm256(
    const unsigned short* __restrict__ A, const unsigned short* __restrict__ Bt,
    void* __restrict__ Cout, const float* __restrict__ bias,
    const float* __restrict__ bias1, const float* __restrict__ bias2,
    const int* __restrict__ mask, int K, int lda, int ldb, int ldc,
    long sA, long sB, long sC, long sM, float scale)
{
    __shared__ unsigned short lds[36864];   // 3 regions x 12288 ushorts = 72KB

    int tn = blockIdx.x;
    const int tm = blockIdx.y, z = blockIdx.z;

    if (QKV) {
        const int g = tn / 10; tn -= g * 10;
        Bt += (size_t)g * sB;
        Cout = (void*)((unsigned short*)Cout + (size_t)g * sC);
        if (g == 1) bias = bias1; else if (g == 2) bias = bias2;
    }

    const unsigned short* Ab = A + (long)z * sA + (size_t)(tm * 256) * lda;
    const unsigned short* Bb = Bt + (QKV ? 0 : (long)z * sB) + (size_t)(tn * 128) * ldb;

    const int tid = threadIdx.x, wave = tid >> 6, l = tid & 63;
    const int wr = wave >> 1, wc = wave & 1;    // 2 x 2 wave grid

    // staging: source chunk pre-swizzled: LDS[r][p] = G[r][p ^ ((r>>1)&3)];
    // all row offsets are multiples of 16 ushorts so swz term = (l>>3)&3.
    const int schunk = ((l & 3) ^ ((l >> 3) & 3)) * 8;
    const unsigned short* agS = Ab + (size_t)(wave * 64 + (l >> 2)) * lda + schunk;
    const unsigned short* bgS = Bb + (size_t)(wave * 32 + (l >> 2)) * ldb + schunk;
    unsigned short* ldsA0 = lds + wave * 2048;          // + region + j*512
    unsigned short* ldsB0 = lds + 8192 + wave * 1024;

    // ds_read offsets (ushort units); row = ...*16 + (l&15) -> swz = (l>>1)&3
    const int rl = l & 15;
    const int cl8 = ((l >> 4) ^ ((l >> 1) & 3)) * 8;
    const int aoff = (wr * 128 + rl) * 32 + cl8;
    const int boff = 8192 + (wc * 64 + rl) * 32 + cl8;

#define SA4(t, bb) { const unsigned short* g_ = agS + (size_t)(t) * 32; \
    GLD16(g_,                     ldsA0 + (bb)); \
    GLD16(g_ + (size_t)16 * lda,  ldsA0 + (bb) + 512); \
    GLD16(g_ + (size_t)32 * lda,  ldsA0 + (bb) + 1024); \
    GLD16(g_ + (size_t)48 * lda,  ldsA0 + (bb) + 1536); }
#define SB2(t, bb) { const unsigned short* g_ = bgS + (size_t)(t) * 32; \
    GLD16(g_,                     ldsB0 + (bb)); \
    GLD16(g_ + (size_t)16 * ldb,  ldsB0 + (bb) + 512); }

    f32x4 acc[8][4] = {};

    // prologue: stage regions 0,1 (12 loads); wait region 0 (oldest 6)
    SA4(0, 0) SB2(0, 0) SA4(1, 12288) SB2(1, 12288)
    asm volatile("s_waitcnt vmcnt(6)" ::: "memory");
    __builtin_amdgcn_s_barrier();

    const int NR = K >> 5;
    int g0 = 0;
    for (int t = 0; t < NR; ++t) {
        const int base = g0 * 12288;
        int g2 = g0 + 2; if (g2 >= 3) g2 -= 3;
        const int base2 = g2 * 12288;
        const bool stg = (t + 2 < NR);   // block-uniform

        // ---- phase A: frags + B-frags, stage A(t+2), MFMA rows 0-3 ----
        short8 af[4], bfv[4];
        #pragma unroll
        for (int n = 0; n < 4; ++n) bfv[n] = *(const short8*)&lds[base + boff + n * 512];
        #pragma unroll
        for (int i = 0; i < 4; ++i) af[i] = *(const short8*)&lds[base + aoff + i * 512];
        if (stg) { SA4(t + 2, base2) }
        __builtin_amdgcn_s_barrier();
        asm volatile("s_waitcnt lgkmcnt(0)" ::: "memory");
        __builtin_amdgcn_sched_barrier(0);
        __builtin_amdgcn_s_setprio(1);
        #pragma unroll
        for (int i = 0; i < 4; ++i)
            #pragma unroll
            for (int n = 0; n < 4; ++n)
                acc[i][n] = __builtin_amdgcn_mfma_f32_16x16x32_bf16(af[i], bfv[n], acc[i][n], 0, 0, 0);
        __builtin_amdgcn_s_setprio(0);
        __builtin_amdgcn_s_barrier();

        // ---- phase B: A rows 4-7, stage B(t+2), MFMA rows 4-7 ----
        #pragma unroll
        for (int i = 0; i < 4; ++i) af[i] = *(const short8*)&lds[base + aoff + (4 + i) * 512];
        if (stg) { SB2(t + 2, base2) }
        __builtin_amdgcn_s_barrier();
        asm volatile("s_waitcnt lgkmcnt(0)" ::: "memory");
        __builtin_amdgcn_sched_barrier(0);
        __builtin_amdgcn_s_setprio(1);
        #pragma unroll
        for (int i = 0; i < 4; ++i)
            #pragma unroll
            for (int n = 0; n < 4; ++n)
                acc[4 + i][n] = __builtin_amdgcn_mfma_f32_16x16x32_bf16(af[i], bfv[n], acc[4 + i][n], 0, 0, 0);
        __builtin_amdgcn_s_setprio(0);
        if (stg)               { asm volatile("s_waitcnt vmcnt(6)" ::: "memory"); }
        else if (t + 1 < NR)   { asm volatile("s_waitcnt vmcnt(0)" ::: "memory"); }
        __builtin_amdgcn_s_barrier();

        g0 = (g0 == 2) ? 0 : g0 + 1;
    }
#undef SA4
#undef SB2

    // epilogue
    const long cb = QKV ? 0 : (long)z * sC;
    const int row0 = tm * 256 + wr * 128 + (l >> 4) * 4;
    const int col0 = tn * 128 + wc * 64 + rl;
    #pragma unroll
    for (int mi = 0; mi < 8; ++mi) {
        #pragma unroll
        for (int n = 0; n < 4; ++n) {
            #pragma unroll
            for (int r = 0; r < 4; ++r) {
                const int row = row0 + mi * 16 + r;
                const int col = col0 + n * 16;
                float v = acc[mi][n][r];
                if (EPI == 0 || EPI == 3) v += bias[col];
                if (EPI == 1) {
                    v *= scale;
                    if (mask[(long)z * sM + (long)row * ldc + col] == 0)
                        v = -1e20f * scale;
                }
                if (EPI == 3)
                    ((float*)Cout)[cb + (long)row * ldc + col] = v;
                else
                    ((unsigned short*)Cout)[cb + (long)row * ldc + col] = f2bf(v);
            }
        }
    }
}

// ---------------------------------------------------------------------------
// Transpose+cast the four 1280x1280 f32 weights -> Wt[j][k] bf16
// ---------------------------------------------------------------------------
__global__ void transpose_w(const float* __restrict__ Wq, const float* __restrict__ Wk,
                            const float* __restrict__ Wv, const float* __restrict__ Wr,
                            unsigned short* __restrict__ Wt)
{
    const float* W = blockIdx.z == 0 ? Wq : blockIdx.z == 1 ? Wk : blockIdx.z == 2 ? Wv : Wr;
    unsigned short* dst = Wt + (size_t)blockIdx.z * 1280 * 1280;
    __shared__ float T[64][65];
    const int j0 = blockIdx.x * 64, k0 = blockIdx.y * 64;
    const int tid = threadIdx.x;
    for (int it = 0; it < 16; ++it) {
        int idx = it * 256 + tid;
        int r = idx >> 6, c = idx & 63;
        T[r][c] = W[(size_t)(k0 + r) * 1280 + j0 + c];
    }
    __syncthreads();
    for (int it = 0; it < 16; ++it) {
        int idx = it * 256 + tid;
        int r = idx >> 6, c = idx & 63;
        dst[(size_t)(j0 + r) * 1280 + k0 + c] = f2bf(T[c][r]);
    }
}

// ---------------------------------------------------------------------------
// Cast x f32 -> bf16, vectorized
// ---------------------------------------------------------------------------
__global__ void cast_x(const float* __restrict__ x, unsigned short* __restrict__ xb, long n)
{
    long i = ((long)blockIdx.x * 256 + threadIdx.x) * 8;
    if (i + 8 > n) return;
    const float4* p = (const float4*)(x + i);
    float4 a = p[0], b = p[1];
    unsigned short o[8] = { f2bf(a.x), f2bf(a.y), f2bf(a.z), f2bf(a.w),
                            f2bf(b.x), f2bf(b.y), f2bf(b.z), f2bf(b.w) };
    *(short8*)(xb + i) = *(short8*)o;
}

// ---------------------------------------------------------------------------
// Row softmax of scaled+masked scores S'[b][m][n] (bf16) and transposed write
// Pt[b][n][m] = softmax_row(S')[m][n].  One block per (64-row strip, batch).
// ---------------------------------------------------------------------------
#define SMS 514
__global__ void softmax_t(const unsigned short* __restrict__ S, unsigned short* __restrict__ Pt)
{
    __shared__ unsigned short T[64 * SMS];
    __shared__ float rmax[64], rinv[64];
    const int b = blockIdx.y, mb = blockIdx.x * 64;
    const int tid = threadIdx.x, lane = tid & 63, wave = tid >> 6;
    const unsigned short* src = S + ((size_t)b * 512 + mb) * 512;

    for (int rr = 0; rr < 16; ++rr) {
        int r = rr * 4 + wave;
        const unsigned int* s = (const unsigned int*)(src + (size_t)r * 512);
        unsigned int* t = (unsigned int*)&T[r * SMS];
        #pragma unroll
        for (int j = 0; j < 4; ++j) t[lane + j * 64] = s[lane + j * 64];
    }
    __syncthreads();

    {   // row stats: 4 threads per row
        int r = tid >> 2, q = tid & 3;
        const unsigned short* row = &T[r * SMS + q * 128];
        float mx = -3.0e38f;
        for (int i = 0; i < 128; ++i) mx = fmaxf(mx, bf2f(row[i]));
        mx = fmaxf(mx, __shfl_xor(mx, 1));
        mx = fmaxf(mx, __shfl_xor(mx, 2));
        float s = 0.f;
        for (int i = 0; i < 128; ++i) s += expf(bf2f(row[i]) - mx);
        s += __shfl_xor(s, 1);
        s += __shfl_xor(s, 2);
        if (q == 0) { rmax[r] = mx; rinv[r] = 1.0f / s; }
    }
    __syncthreads();

    {   // transposed write: lane -> m, groups of 64 -> n
        int m = tid & 63, nq = tid >> 6;
        float mxm = rmax[m], rim = rinv[m];
        unsigned short* dst = Pt + (size_t)b * 512 * 512 + mb + m;
        for (int it = 0; it < 128; ++it) {
            int n = it * 4 + nq;
            float v = expf(bf2f(T[m * SMS + n]) - mxm) * rim;
            dst[(size_t)n * 512] = f2bf(v);
        }
    }
}

// ---------------------------------------------------------------------------
// Per-batch transpose V[b][m][c] -> Vt[b][c][m]  (bf16)
// ---------------------------------------------------------------------------
__global__ void transpose_v(const unsigned short* __restrict__ V, unsigned short* __restrict__ Vt)
{
    __shared__ unsigned short T[64][65];
    const int b = blockIdx.z;
    const int c0 = blockIdx.x * 64, m0 = blockIdx.y * 64;
    const int tid = threadIdx.x;
    const unsigned short* src = V + ((size_t)b * 512 + m0) * 1280 + c0;
    for (int it = 0; it < 16; ++it) {
        int idx = it * 256 + tid;
        int r = idx >> 6, c = idx & 63;
        T[r][c] = src[(size_t)r * 1280 + c];
    }
    __syncthreads();
    unsigned short* dst = Vt + ((size_t)b * 1280 + c0) * 512 + m0;
    for (int it = 0; it < 16; ++it) {
        int idx = it * 256 + tid;
        int r = idx >> 6, c = idx & 63;
        dst[(size_t)r * 512 + c] = T[c][r];
    }
}

// ---------------------------------------------------------------------------
extern "C" void kernel_launch(void* const* d_in, const int* in_sizes, int n_in,
                              void* d_out, int out_size, void* d_ws, size_t ws_size,
                              hipStream_t stream)
{
    const float* x   = (const float*)d_in[0];
    const int*  Mask = (const int*)d_in[1];
    const float* Wq  = (const float*)d_in[2];
    const float* bq  = (const float*)d_in[3];
    const float* Wk  = (const float*)d_in[4];
    const float* bk  = (const float*)d_in[5];
    const float* Wv  = (const float*)d_in[6];
    const float* bv  = (const float*)d_in[7];
    const float* Wr  = (const float*)d_in[8];
    const float* br  = (const float*)d_in[9];

    constexpr int N = 512, C = 1280;
    constexpr long MN = 32768;   // B*N

    char* ws = (char*)d_ws;
    unsigned short* xb = (unsigned short*)ws;                         // MN*C bf16 (later: att)
    unsigned short* Wt = (unsigned short*)(ws + 83886080);            // 4*C*C bf16
    unsigned short* Q  = (unsigned short*)(ws + 83886080 + 13107200); // MN*C (later: Vt)
    unsigned short* Km = Q + 41943040;
    unsigned short* V  = Km + 41943040;
    unsigned short* Sp = V + 41943040;                                // B*N*N
    unsigned short* Pt = Sp + 16777216;                               // B*N*N
    unsigned short* Vt = Q;     // alias: Q dead after scores GEMM
    unsigned short* att = xb;   // alias: xb dead after QKV GEMMs

    const float scale = 0.02795084971874737f;   // 1/sqrt(1280)

    transpose_w<<<dim3(20, 20, 4), 256, 0, stream>>>(Wq, Wk, Wv, Wr, Wt);
    cast_x<<<dim3(20480), 256, 0, stream>>>(x, xb, MN * C);

    // fused QKV projections: M=32768, N=3x1280, K=1280; x/10 selects group
    gemm256<0, 1><<<dim3(30, 128, 1), 256, 0, stream>>>(xb, Wt, (void*)Q, bq, bk, bv,
        nullptr, C, C, C, C, 0, 1638400L, 41943040L, 0, 0.f);

    // scores: S'[b][i][j] = scale * (Q[b][i] . K[b][j]), masked
    gemm256<1, 0><<<dim3(4, 2, 64), 256, 0, stream>>>(Q, Km, (void*)Sp, nullptr, nullptr, nullptr,
        Mask, C, C, C, N, (long)N * C, (long)N * C, (long)N * N, (long)N * N, scale);

    // softmax rows + transposed store Pt[b][n][m]
    softmax_t<<<dim3(8, 64), 256, 0, stream>>>(Sp, Pt);

    // Vt[b][c][m]
    transpose_v<<<dim3(20, 8, 64), 256, 0, stream>>>(V, Vt);

    // att[b][n][c] = sum_m Pt[b][n][m] * Vt[b][c][m]   (M=512, N=1280, K=512)
    gemm256<2, 0><<<dim3(10, 2, 64), 256, 0, stream>>>(Pt, Vt, (void*)att, nullptr, nullptr, nullptr,
        nullptr, N, N, N, C, (long)N * N, (long)C * N, (long)N * C, 0, 0.f);

    // out = att @ Wr + br   (f32)
    gemm256<3, 0><<<dim3(10, 128, 1), 256, 0, stream>>>(att, Wt + 3 * 1638400, d_out, br, nullptr, nullptr,
        nullptr, C, C, C, C, 0, 0, 0, 0, 0.f);
}

// Round 5
// 730.398 us; speedup vs baseline: 1.4300x; 1.0698x over previous
//
#include <hip/hip_runtime.h>
#include <hip/hip_bf16.h>

#define DI __device__ __forceinline__

typedef __attribute__((ext_vector_type(8))) short short8;
typedef __attribute__((ext_vector_type(4))) float f32x4;

DI unsigned short f2bf(float f) {
    union { float f; unsigned int u; } v; v.f = f;
    unsigned int r = v.u + 0x7FFFu + ((v.u >> 16) & 1u);
    return (unsigned short)(r >> 16);
}
DI float bf2f(unsigned short h) {
    union { unsigned int u; float f; } v; v.u = ((unsigned int)h) << 16;
    return v.f;
}

#define GLD16(g, l) __builtin_amdgcn_global_load_lds( \
    (const __attribute__((address_space(1))) void*)(g), \
    (__attribute__((address_space(3))) void*)(l), 16, 0, 0)

// ---------------------------------------------------------------------------
// 256x128 NT GEMM, 256 threads (4 waves, 2Mx2N; per-wave 128x64), rotation-3
// K-region pipeline (region = 32 k-cols: A 256x32 + B 128x32 = 24KB), 72KB LDS
// -> 2 blocks/CU.  C[i][j] = sum_k A[i][k]*Bt[j][k].
// Swizzle: LDS[r][p] = G[r][p ^ ((r>>1)&3)] (conflict-free, verified r3).
// XCD chunking: flattened grid remapped lin -> (lin&7)*(nwg/8)+(lin>>3) so
// each XCD gets a contiguous tile range (A-panel fetched into ONE L2, not 8).
// Requires nwg % 8 == 0 for all launches.
// EPI: 0 = +bias->bf16, 1 = *scale+mask->bf16, 2 = plain bf16, 3 = +bias->f32
// QKV=1: tn in [0,30); g = tn/10 selects Bt/Cout/bias.
// Requires: M%256==0, N%128==0, K%32==0, K>=64.
// ---------------------------------------------------------------------------
template<int EPI, int QKV>
__global__ __launch_bounds__(256, 2) void gemm256(
    const unsigned short* __restrict__ A, const unsigned short* __restrict__ Bt,
    void* __restrict__ Cout, const float* __restrict__ bias,
    const float* __restrict__ bias1, const float* __restrict__ bias2,
    const int* __restrict__ mask, int K, int lda, int ldb, int ldc,
    long sA, long sB, long sC, long sM, float scale)
{
    __shared__ unsigned short lds[36864];   // 3 regions x 12288 ushorts = 72KB

    // XCD-chunked bijective remap of the flattened grid (nwg % 8 == 0)
    const unsigned gx = gridDim.x, gy = gridDim.y;
    unsigned lin = blockIdx.x + gx * (blockIdx.y + gy * blockIdx.z);
    const unsigned nwg = gx * gy * gridDim.z;
    lin = (lin & 7u) * (nwg >> 3) + (lin >> 3);
    int tn = lin % gx;
    const int tm = (lin / gx) % gy;
    const int z = lin / (gx * gy);

    if (QKV) {
        const int g = tn / 10; tn -= g * 10;
        Bt += (size_t)g * sB;
        Cout = (void*)((unsigned short*)Cout + (size_t)g * sC);
        if (g == 1) bias = bias1; else if (g == 2) bias = bias2;
    }

    const unsigned short* Ab = A + (long)z * sA + (size_t)(tm * 256) * lda;
    const unsigned short* Bb = Bt + (QKV ? 0 : (long)z * sB) + (size_t)(tn * 128) * ldb;

    const int tid = threadIdx.x, wave = tid >> 6, l = tid & 63;
    const int wr = wave >> 1, wc = wave & 1;    // 2 x 2 wave grid

    // staging: source chunk pre-swizzled: LDS[r][p] = G[r][p ^ ((r>>1)&3)];
    // all row offsets are multiples of 16 ushorts so swz term = (l>>3)&3.
    const int schunk = ((l & 3) ^ ((l >> 3) & 3)) * 8;
    const unsigned short* agS = Ab + (size_t)(wave * 64 + (l >> 2)) * lda + schunk;
    const unsigned short* bgS = Bb + (size_t)(wave * 32 + (l >> 2)) * ldb + schunk;
    unsigned short* ldsA0 = lds + wave * 2048;          // + region + j*512
    unsigned short* ldsB0 = lds + 8192 + wave * 1024;

    // ds_read offsets (ushort units); row = ...*16 + (l&15) -> swz = (l>>1)&3
    const int rl = l & 15;
    const int cl8 = ((l >> 4) ^ ((l >> 1) & 3)) * 8;
    const int aoff = (wr * 128 + rl) * 32 + cl8;
    const int boff = 8192 + (wc * 64 + rl) * 32 + cl8;

#define SA4(t, bb) { const unsigned short* g_ = agS + (size_t)(t) * 32; \
    GLD16(g_,                     ldsA0 + (bb)); \
    GLD16(g_ + (size_t)16 * lda,  ldsA0 + (bb) + 512); \
    GLD16(g_ + (size_t)32 * lda,  ldsA0 + (bb) + 1024); \
    GLD16(g_ + (size_t)48 * lda,  ldsA0 + (bb) + 1536); }
#define SB2(t, bb) { const unsigned short* g_ = bgS + (size_t)(t) * 32; \
    GLD16(g_,                     ldsB0 + (bb)); \
    GLD16(g_ + (size_t)16 * ldb,  ldsB0 + (bb) + 512); }

    f32x4 acc[8][4] = {};

    // prologue: stage regions 0,1 (12 loads); wait region 0 (oldest 6)
    SA4(0, 0) SB2(0, 0) SA4(1, 12288) SB2(1, 12288)
    asm volatile("s_waitcnt vmcnt(6)" ::: "memory");
    __builtin_amdgcn_s_barrier();

    const int NR = K >> 5;
    int g0 = 0;
    for (int t = 0; t < NR; ++t) {
        const int base = g0 * 12288;
        int g2 = g0 + 2; if (g2 >= 3) g2 -= 3;
        const int base2 = g2 * 12288;
        const bool stg = (t + 2 < NR);   // block-uniform

        // ---- phase A: frags + B-frags, stage A(t+2), MFMA rows 0-3 ----
        short8 af[4], bfv[4];
        #pragma unroll
        for (int n = 0; n < 4; ++n) bfv[n] = *(const short8*)&lds[base + boff + n * 512];
        #pragma unroll
        for (int i = 0; i < 4; ++i) af[i] = *(const short8*)&lds[base + aoff + i * 512];
        if (stg) { SA4(t + 2, base2) }
        __builtin_amdgcn_s_barrier();
        asm volatile("s_waitcnt lgkmcnt(0)" ::: "memory");
        __builtin_amdgcn_sched_barrier(0);
        __builtin_amdgcn_s_setprio(1);
        #pragma unroll
        for (int i = 0; i < 4; ++i)
            #pragma unroll
            for (int n = 0; n < 4; ++n)
                acc[i][n] = __builtin_amdgcn_mfma_f32_16x16x32_bf16(af[i], bfv[n], acc[i][n], 0, 0, 0);
        __builtin_amdgcn_s_setprio(0);
        __builtin_amdgcn_s_barrier();

        // ---- phase B: A rows 4-7, stage B(t+2), MFMA rows 4-7 ----
        #pragma unroll
        for (int i = 0; i < 4; ++i) af[i] = *(const short8*)&lds[base + aoff + (4 + i) * 512];
        if (stg) { SB2(t + 2, base2) }
        __builtin_amdgcn_s_barrier();
        asm volatile("s_waitcnt lgkmcnt(0)" ::: "memory");
        __builtin_amdgcn_sched_barrier(0);
        __builtin_amdgcn_s_setprio(1);
        #pragma unroll
        for (int i = 0; i < 4; ++i)
            #pragma unroll
            for (int n = 0; n < 4; ++n)
                acc[4 + i][n] = __builtin_amdgcn_mfma_f32_16x16x32_bf16(af[i], bfv[n], acc[4 + i][n], 0, 0, 0);
        __builtin_amdgcn_s_setprio(0);
        if (stg)               { asm volatile("s_waitcnt vmcnt(6)" ::: "memory"); }
        else if (t + 1 < NR)   { asm volatile("s_waitcnt vmcnt(0)" ::: "memory"); }
        __builtin_amdgcn_s_barrier();

        g0 = (g0 == 2) ? 0 : g0 + 1;
    }
#undef SA4
#undef SB2

    // epilogue
    const long cb = QKV ? 0 : (long)z * sC;
    const int row0 = tm * 256 + wr * 128 + (l >> 4) * 4;
    const int col0 = tn * 128 + wc * 64 + rl;
    #pragma unroll
    for (int mi = 0; mi < 8; ++mi) {
        #pragma unroll
        for (int n = 0; n < 4; ++n) {
            #pragma unroll
            for (int r = 0; r < 4; ++r) {
                const int row = row0 + mi * 16 + r;
                const int col = col0 + n * 16;
                float v = acc[mi][n][r];
                if (EPI == 0 || EPI == 3) v += bias[col];
                if (EPI == 1) {
                    v *= scale;
                    if (mask[(long)z * sM + (long)row * ldc + col] == 0)
                        v = -1e20f * scale;
                }
                if (EPI == 3)
                    ((float*)Cout)[cb + (long)row * ldc + col] = v;
                else
                    ((unsigned short*)Cout)[cb + (long)row * ldc + col] = f2bf(v);
            }
        }
    }
}

// ---------------------------------------------------------------------------
// Transpose+cast the four 1280x1280 f32 weights -> Wt[j][k] bf16
// ---------------------------------------------------------------------------
__global__ void transpose_w(const float* __restrict__ Wq, const float* __restrict__ Wk,
                            const float* __restrict__ Wv, const float* __restrict__ Wr,
                            unsigned short* __restrict__ Wt)
{
    const float* W = blockIdx.z == 0 ? Wq : blockIdx.z == 1 ? Wk : blockIdx.z == 2 ? Wv : Wr;
    unsigned short* dst = Wt + (size_t)blockIdx.z * 1280 * 1280;
    __shared__ float T[64][65];
    const int j0 = blockIdx.x * 64, k0 = blockIdx.y * 64;
    const int tid = threadIdx.x;
    for (int it = 0; it < 16; ++it) {
        int idx = it * 256 + tid;
        int r = idx >> 6, c = idx & 63;
        T[r][c] = W[(size_t)(k0 + r) * 1280 + j0 + c];
    }
    __syncthreads();
    for (int it = 0; it < 16; ++it) {
        int idx = it * 256 + tid;
        int r = idx >> 6, c = idx & 63;
        dst[(size_t)(j0 + r) * 1280 + k0 + c] = f2bf(T[c][r]);
    }
}

// ---------------------------------------------------------------------------
// Cast x f32 -> bf16, vectorized
// ---------------------------------------------------------------------------
__global__ void cast_x(const float* __restrict__ x, unsigned short* __restrict__ xb, long n)
{
    long i = ((long)blockIdx.x * 256 + threadIdx.x) * 8;
    if (i + 8 > n) return;
    const float4* p = (const float4*)(x + i);
    float4 a = p[0], b = p[1];
    unsigned short o[8] = { f2bf(a.x), f2bf(a.y), f2bf(a.z), f2bf(a.w),
                            f2bf(b.x), f2bf(b.y), f2bf(b.z), f2bf(b.w) };
    *(short8*)(xb + i) = *(short8*)o;
}

// ---------------------------------------------------------------------------
// Row softmax of scaled+masked scores S'[b][m][n] (bf16) and transposed write
// Pt[b][n][m] = softmax_row(S')[m][n].  One block per (64-row strip, batch).
// ---------------------------------------------------------------------------
#define SMS 514
__global__ void softmax_t(const unsigned short* __restrict__ S, unsigned short* __restrict__ Pt)
{
    __shared__ unsigned short T[64 * SMS];
    __shared__ float rmax[64], rinv[64];
    const int b = blockIdx.y, mb = blockIdx.x * 64;
    const int tid = threadIdx.x, lane = tid & 63, wave = tid >> 6;
    const unsigned short* src = S + ((size_t)b * 512 + mb) * 512;

    for (int rr = 0; rr < 16; ++rr) {
        int r = rr * 4 + wave;
        const unsigned int* s = (const unsigned int*)(src + (size_t)r * 512);
        unsigned int* t = (unsigned int*)&T[r * SMS];
        #pragma unroll
        for (int j = 0; j < 4; ++j) t[lane + j * 64] = s[lane + j * 64];
    }
    __syncthreads();

    {   // row stats: 4 threads per row
        int r = tid >> 2, q = tid & 3;
        const unsigned short* row = &T[r * SMS + q * 128];
        float mx = -3.0e38f;
        for (int i = 0; i < 128; ++i) mx = fmaxf(mx, bf2f(row[i]));
        mx = fmaxf(mx, __shfl_xor(mx, 1));
        mx = fmaxf(mx, __shfl_xor(mx, 2));
        float s = 0.f;
        for (int i = 0; i < 128; ++i) s += expf(bf2f(row[i]) - mx);
        s += __shfl_xor(s, 1);
        s += __shfl_xor(s, 2);
        if (q == 0) { rmax[r] = mx; rinv[r] = 1.0f / s; }
    }
    __syncthreads();

    {   // transposed write: lane -> m, groups of 64 -> n
        int m = tid & 63, nq = tid >> 6;
        float mxm = rmax[m], rim = rinv[m];
        unsigned short* dst = Pt + (size_t)b * 512 * 512 + mb + m;
        for (int it = 0; it < 128; ++it) {
            int n = it * 4 + nq;
            float v = expf(bf2f(T[m * SMS + n]) - mxm) * rim;
            dst[(size_t)n * 512] = f2bf(v);
        }
    }
}

// ---------------------------------------------------------------------------
// Per-batch transpose V[b][m][c] -> Vt[b][c][m]  (bf16)
// ---------------------------------------------------------------------------
__global__ void transpose_v(const unsigned short* __restrict__ V, unsigned short* __restrict__ Vt)
{
    __shared__ unsigned short T[64][65];
    const int b = blockIdx.z;
    const int c0 = blockIdx.x * 64, m0 = blockIdx.y * 64;
    const int tid = threadIdx.x;
    const unsigned short* src = V + ((size_t)b * 512 + m0) * 1280 + c0;
    for (int it = 0; it < 16; ++it) {
        int idx = it * 256 + tid;
        int r = idx >> 6, c = idx & 63;
        T[r][c] = src[(size_t)r * 1280 + c];
    }
    __syncthreads();
    unsigned short* dst = Vt + ((size_t)b * 1280 + c0) * 512 + m0;
    for (int it = 0; it < 16; ++it) {
        int idx = it * 256 + tid;
        int r = idx >> 6, c = idx & 63;
        dst[(size_t)r * 512 + c] = T[c][r];
    }
}

// ---------------------------------------------------------------------------
extern "C" void kernel_launch(void* const* d_in, const int* in_sizes, int n_in,
                              void* d_out, int out_size, void* d_ws, size_t ws_size,
                              hipStream_t stream)
{
    const float* x   = (const float*)d_in[0];
    const int*  Mask = (const int*)d_in[1];
    const float* Wq  = (const float*)d_in[2];
    const float* bq  = (const float*)d_in[3];
    const float* Wk  = (const float*)d_in[4];
    const float* bk  = (const float*)d_in[5];
    const float* Wv  = (const float*)d_in[6];
    const float* bv  = (const float*)d_in[7];
    const float* Wr  = (const float*)d_in[8];
    const float* br  = (const float*)d_in[9];

    constexpr int N = 512, C = 1280;
    constexpr long MN = 32768;   // B*N

    char* ws = (char*)d_ws;
    unsigned short* xb = (unsigned short*)ws;                         // MN*C bf16 (later: att)
    unsigned short* Wt = (unsigned short*)(ws + 83886080);            // 4*C*C bf16
    unsigned short* Q  = (unsigned short*)(ws + 83886080 + 13107200); // MN*C (later: Vt)
    unsigned short* Km = Q + 41943040;
    unsigned short* V  = Km + 41943040;
    unsigned short* Sp = V + 41943040;                                // B*N*N
    unsigned short* Pt = Sp + 16777216;                               // B*N*N
    unsigned short* Vt = Q;     // alias: Q dead after scores GEMM
    unsigned short* att = xb;   // alias: xb dead after QKV GEMMs

    const float scale = 0.02795084971874737f;   // 1/sqrt(1280)

    transpose_w<<<dim3(20, 20, 4), 256, 0, stream>>>(Wq, Wk, Wv, Wr, Wt);
    cast_x<<<dim3(20480), 256, 0, stream>>>(x, xb, MN * C);

    // fused QKV projections: M=32768, N=3x1280, K=1280; tn/10 selects group
    gemm256<0, 1><<<dim3(30, 128, 1), 256, 0, stream>>>(xb, Wt, (void*)Q, bq, bk, bv,
        nullptr, C, C, C, C, 0, 1638400L, 41943040L, 0, 0.f);

    // scores: S'[b][i][j] = scale * (Q[b][i] . K[b][j]), masked
    gemm256<1, 0><<<dim3(4, 2, 64), 256, 0, stream>>>(Q, Km, (void*)Sp, nullptr, nullptr, nullptr,
        Mask, C, C, C, N, (long)N * C, (long)N * C, (long)N * N, (long)N * N, scale);

    // softmax rows + transposed store Pt[b][n][m]
    softmax_t<<<dim3(8, 64), 256, 0, stream>>>(Sp, Pt);

    // Vt[b][c][m]
    transpose_v<<<dim3(20, 8, 64), 256, 0, stream>>>(V, Vt);

    // att[b][n][c] = sum_m Pt[b][n][m] * Vt[b][c][m]   (M=512, N=1280, K=512)
    gemm256<2, 0><<<dim3(10, 2, 64), 256, 0, stream>>>(Pt, Vt, (void*)att, nullptr, nullptr, nullptr,
        nullptr, N, N, N, C, (long)N * N, (long)C * N, (long)N * C, 0, 0.f);

    // out = att @ Wr + br   (f32)
    gemm256<3, 0><<<dim3(10, 128, 1), 256, 0, stream>>>(att, Wt + 3 * 1638400, d_out, br, nullptr, nullptr,
        nullptr, C, C, C, C, 0, 0, 0, 0, 0.f);
}

// Round 6
// 722.500 us; speedup vs baseline: 1.4456x; 1.0109x over previous
//
#include <hip/hip_runtime.h>
#include <hip/hip_bf16.h>

#define DI __device__ __forceinline__

typedef __attribute__((ext_vector_type(8))) short short8;
typedef __attribute__((ext_vector_type(4))) float f32x4;

DI unsigned short f2bf(float f) {
    union { float f; unsigned int u; } v; v.f = f;
    unsigned int r = v.u + 0x7FFFu + ((v.u >> 16) & 1u);
    return (unsigned short)(r >> 16);
}
DI float bf2f(unsigned short h) {
    union { unsigned int u; float f; } v; v.u = ((unsigned int)h) << 16;
    return v.f;
}

#define GLD16(g, l) __builtin_amdgcn_global_load_lds( \
    (const __attribute__((address_space(1))) void*)(g), \
    (__attribute__((address_space(3))) void*)(l), 16, 0, 0)

// ---------------------------------------------------------------------------
// 256x256 8-phase NT GEMM, BK=64, 8 waves (2Mx4N), 128KiB LDS, 1 block/CU.
// C[i][j] = sum_k A[i][k] * Bt[j][k]
// Swizzle (verified conflict-free r4/r5): LDS[r][p] = G[r][p ^ ((r>>1)&3)]
//   (LDS rows are 64B -> bank period 2 rows; XOR row bits [2:1] into the
//   16B-chunk index makes each 8-lane b128 quarter-group cover 32 banks).
// XCD chunking (bijective, nwg%8==0): lin -> (lin&7)*(nwg/8)+(lin>>3); grid
//   x = N-tile (fastest) so same-A-panel blocks are contiguous per XCD.
// Counted vmcnt(8) per phase; drain 8->4->0 only in peeled last iteration.
// EPI: 0 = +bias->bf16, 1 = *scale+mask->bf16, 2 = plain bf16, 3 = +bias->f32
// QKV=1: tn in [0,15); g = tn/5 selects Bt/Cout/bias.
// Requires: M%256==0, N%256==0, K%128==0, K>=256.
// ---------------------------------------------------------------------------
template<int EPI, int QKV>
__global__ __launch_bounds__(512, 2) void gemm256(
    const unsigned short* __restrict__ A, const unsigned short* __restrict__ Bt,
    void* __restrict__ Cout, const float* __restrict__ bias,
    const float* __restrict__ bias1, const float* __restrict__ bias2,
    const int* __restrict__ mask, int K, int lda, int ldb, int ldc,
    long sA, long sB, long sC, long sM, float scale)
{
    __shared__ unsigned short lds[65536];   // 128 KiB

    // XCD-chunked bijective remap of the flattened grid (nwg % 8 == 0)
    const unsigned gx = gridDim.x, gy = gridDim.y;
    unsigned lin = blockIdx.x + gx * (blockIdx.y + gy * blockIdx.z);
    const unsigned nwg = gx * gy * gridDim.z;
    lin = (lin & 7u) * (nwg >> 3) + (lin >> 3);
    int tn = lin % gx;
    const int tm = (lin / gx) % gy;
    const int z = lin / (gx * gy);

    if (QKV) {
        const int g = tn / 5; tn -= g * 5;
        Bt += (size_t)g * sB;
        Cout = (void*)((unsigned short*)Cout + (size_t)g * sC);
        if (g == 1) bias = bias1; else if (g == 2) bias = bias2;
    }

    const unsigned short* Ab = A + (long)z * sA + (size_t)(tm * 256) * lda;
    const unsigned short* Bb = Bt + (QKV ? 0 : (long)z * sB) + (size_t)(tn * 256) * ldb;

    const int tid = threadIdx.x, wave = tid >> 6, l = tid & 63;
    const int wr = wave >> 2, wc = wave & 3;    // 2 x 4 wave grid

    // staging: wave covers rows [wave*32, wave*32+32); lane l -> row +(l>>2);
    // source chunk pre-swizzled: LDS[r][p] = G[r][p ^ ((r>>1)&3)]; row = l>>2
    // so swz term = (l>>3)&3
    const int srow = wave * 32 + (l >> 2);
    const int schunk = ((l & 3) ^ ((l >> 3) & 3)) * 8;
    const unsigned short* agS = Ab + (size_t)srow * lda + schunk;
    const unsigned short* bgS = Bb + (size_t)srow * ldb + schunk;
    unsigned short* ldsA0 = &lds[wave * 1024];
    unsigned short* ldsB0 = &lds[8192 + wave * 1024];

    // ds_read offsets (ushort units); row = mult16 + (l&15) -> swz = (l>>1)&3
    const int rl = l & 15;
    const int cl8 = ((l >> 4) ^ ((l >> 1) & 3)) * 8;
    const int aoff = (wr * 128 + rl) * 32 + cl8;
    const int boff = 8192 + (wc * 64 + rl) * 32 + cl8;

#define REGOFF(buf, h) (((buf) * 2 + (h)) * 16384)
#define SA(t, h, buf) { const unsigned short* g_ = agS + (size_t)((t) * 64 + (h) * 32); \
    GLD16(g_, ldsA0 + REGOFF(buf, h)); \
    GLD16(g_ + (size_t)16 * lda, ldsA0 + REGOFF(buf, h) + 512); }
#define SB(t, h, buf) { const unsigned short* g_ = bgS + (size_t)((t) * 64 + (h) * 32); \
    GLD16(g_, ldsB0 + REGOFF(buf, h)); \
    GLD16(g_ + (size_t)16 * ldb, ldsB0 + REGOFF(buf, h) + 512); }

    f32x4 acc[8][4] = {};
    short8 bfr[4];

#define PHASE(mg, h, buf, RDB, STG, VMW) { \
    short8 af[4]; \
    if (RDB) { \
        _Pragma("unroll") for (int n = 0; n < 4; ++n) \
            bfr[n] = *(const short8*)&lds[REGOFF(buf, h) + boff + n * 512]; \
    } \
    _Pragma("unroll") for (int i = 0; i < 4; ++i) \
        af[i] = *(const short8*)&lds[REGOFF(buf, h) + aoff + ((mg) * 4 + i) * 512]; \
    STG; \
    __builtin_amdgcn_s_barrier(); \
    asm volatile("s_waitcnt lgkmcnt(0)" ::: "memory"); \
    __builtin_amdgcn_sched_barrier(0); \
    __builtin_amdgcn_s_setprio(1); \
    _Pragma("unroll") for (int i = 0; i < 4; ++i) \
        _Pragma("unroll") for (int n = 0; n < 4; ++n) \
            acc[(mg) * 4 + i][n] = __builtin_amdgcn_mfma_f32_16x16x32_bf16( \
                af[i], bfr[n], acc[(mg) * 4 + i][n], 0, 0, 0); \
    __builtin_amdgcn_s_setprio(0); \
    asm volatile("s_waitcnt " VMW ::: "memory"); \
    __builtin_amdgcn_s_barrier(); \
  }

    // prologue: tile0 full + tile1 k0  (12 loads); drain tile0.k0 (oldest 4)
    SA(0, 0, 0); SB(0, 0, 0); SA(0, 1, 0); SB(0, 1, 0); SA(1, 0, 1); SB(1, 0, 1);
    asm volatile("s_waitcnt vmcnt(8)" ::: "memory");
    __builtin_amdgcn_s_barrier();

    const int NI = K >> 7;          // iterations, 2 K-tiles (BK=64) each
    for (int j = 0; j < NI - 1; ++j) {
        const int t = 2 * j;
        PHASE(0, 0, 0, 1, SA(t + 1, 1, 1), "vmcnt(8)")
        PHASE(1, 0, 0, 0, SB(t + 1, 1, 1), "vmcnt(8)")
        PHASE(0, 1, 0, 1, SA(t + 2, 0, 0), "vmcnt(8)")
        PHASE(1, 1, 0, 0, SB(t + 2, 0, 0), "vmcnt(8)")
        PHASE(0, 0, 1, 1, SA(t + 2, 1, 0), "vmcnt(8)")
        PHASE(1, 0, 1, 0, SB(t + 2, 1, 0), "vmcnt(8)")
        PHASE(0, 1, 1, 1, SA(t + 3, 0, 1), "vmcnt(8)")
        PHASE(1, 1, 1, 0, SB(t + 3, 0, 1), "vmcnt(8)")
    }
    {   // peeled last iteration: stage only tile NT-1 k1; drain 8 -> 4 -> 0
        const int t = 2 * (NI - 1);
        PHASE(0, 0, 0, 1, SA(t + 1, 1, 1), "vmcnt(8)")
        PHASE(1, 0, 0, 0, SB(t + 1, 1, 1), "vmcnt(8)")
        PHASE(0, 1, 0, 1, ((void)0),       "vmcnt(8)")
        PHASE(1, 1, 0, 0, ((void)0),       "vmcnt(4)")
        PHASE(0, 0, 1, 1, ((void)0),       "vmcnt(4)")
        PHASE(1, 0, 1, 0, ((void)0),       "vmcnt(0)")
        PHASE(0, 1, 1, 1, ((void)0),       "vmcnt(0)")
        PHASE(1, 1, 1, 0, ((void)0),       "vmcnt(0)")
    }
#undef PHASE
#undef SA
#undef SB
#undef REGOFF

    // epilogue
    const long cb = QKV ? 0 : (long)z * sC;
    const int row0 = tm * 256 + wr * 128 + (l >> 4) * 4;
    const int col0 = tn * 256 + wc * 64 + rl;
    #pragma unroll
    for (int mi = 0; mi < 8; ++mi) {
        #pragma unroll
        for (int n = 0; n < 4; ++n) {
            #pragma unroll
            for (int r = 0; r < 4; ++r) {
                const int row = row0 + mi * 16 + r;
                const int col = col0 + n * 16;
                float v = acc[mi][n][r];
                if (EPI == 0 || EPI == 3) v += bias[col];
                if (EPI == 1) {
                    v *= scale;
                    if (mask[(long)z * sM + (long)row * ldc + col] == 0)
                        v = -1e20f * scale;
                }
                if (EPI == 3)
                    ((float*)Cout)[cb + (long)row * ldc + col] = v;
                else
                    ((unsigned short*)Cout)[cb + (long)row * ldc + col] = f2bf(v);
            }
        }
    }
}

// ---------------------------------------------------------------------------
// Transpose+cast the four 1280x1280 f32 weights -> Wt[j][k] bf16
// ---------------------------------------------------------------------------
__global__ void transpose_w(const float* __restrict__ Wq, const float* __restrict__ Wk,
                            const float* __restrict__ Wv, const float* __restrict__ Wr,
                            unsigned short* __restrict__ Wt)
{
    const float* W = blockIdx.z == 0 ? Wq : blockIdx.z == 1 ? Wk : blockIdx.z == 2 ? Wv : Wr;
    unsigned short* dst = Wt + (size_t)blockIdx.z * 1280 * 1280;
    __shared__ float T[64][65];
    const int j0 = blockIdx.x * 64, k0 = blockIdx.y * 64;
    const int tid = threadIdx.x;
    for (int it = 0; it < 16; ++it) {
        int idx = it * 256 + tid;
        int r = idx >> 6, c = idx & 63;
        T[r][c] = W[(size_t)(k0 + r) * 1280 + j0 + c];
    }
    __syncthreads();
    for (int it = 0; it < 16; ++it) {
        int idx = it * 256 + tid;
        int r = idx >> 6, c = idx & 63;
        dst[(size_t)(j0 + r) * 1280 + k0 + c] = f2bf(T[c][r]);
    }
}

// ---------------------------------------------------------------------------
// Cast x f32 -> bf16, vectorized
// ---------------------------------------------------------------------------
__global__ void cast_x(const float* __restrict__ x, unsigned short* __restrict__ xb, long n)
{
    long i = ((long)blockIdx.x * 256 + threadIdx.x) * 8;
    if (i + 8 > n) return;
    const float4* p = (const float4*)(x + i);
    float4 a = p[0], b = p[1];
    unsigned short o[8] = { f2bf(a.x), f2bf(a.y), f2bf(a.z), f2bf(a.w),
                            f2bf(b.x), f2bf(b.y), f2bf(b.z), f2bf(b.w) };
    *(short8*)(xb + i) = *(short8*)o;
}

// ---------------------------------------------------------------------------
// Row softmax of scaled+masked scores S'[b][m][n] (bf16) and transposed write
// Pt[b][n][m] = softmax_row(S')[m][n].  One block per (64-row strip, batch).
// ---------------------------------------------------------------------------
#define SMS 514
__global__ void softmax_t(const unsigned short* __restrict__ S, unsigned short* __restrict__ Pt)
{
    __shared__ unsigned short T[64 * SMS];
    __shared__ float rmax[64], rinv[64];
    const int b = blockIdx.y, mb = blockIdx.x * 64;
    const int tid = threadIdx.x, lane = tid & 63, wave = tid >> 6;
    const unsigned short* src = S + ((size_t)b * 512 + mb) * 512;

    for (int rr = 0; rr < 16; ++rr) {
        int r = rr * 4 + wave;
        const unsigned int* s = (const unsigned int*)(src + (size_t)r * 512);
        unsigned int* t = (unsigned int*)&T[r * SMS];
        #pragma unroll
        for (int j = 0; j < 4; ++j) t[lane + j * 64] = s[lane + j * 64];
    }
    __syncthreads();

    {   // row stats: 4 threads per row
        int r = tid >> 2, q = tid & 3;
        const unsigned short* row = &T[r * SMS + q * 128];
        float mx = -3.0e38f;
        for (int i = 0; i < 128; ++i) mx = fmaxf(mx, bf2f(row[i]));
        mx = fmaxf(mx, __shfl_xor(mx, 1));
        mx = fmaxf(mx, __shfl_xor(mx, 2));
        float s = 0.f;
        for (int i = 0; i < 128; ++i) s += expf(bf2f(row[i]) - mx);
        s += __shfl_xor(s, 1);
        s += __shfl_xor(s, 2);
        if (q == 0) { rmax[r] = mx; rinv[r] = 1.0f / s; }
    }
    __syncthreads();

    {   // transposed write: lane -> m, groups of 64 -> n
        int m = tid & 63, nq = tid >> 6;
        float mxm = rmax[m], rim = rinv[m];
        unsigned short* dst = Pt + (size_t)b * 512 * 512 + mb + m;
        for (int it = 0; it < 128; ++it) {
            int n = it * 4 + nq;
            float v = expf(bf2f(T[m * SMS + n]) - mxm) * rim;
            dst[(size_t)n * 512] = f2bf(v);
        }
    }
}

// ---------------------------------------------------------------------------
// Per-batch transpose V[b][m][c] -> Vt[b][c][m]  (bf16)
// ---------------------------------------------------------------------------
__global__ void transpose_v(const unsigned short* __restrict__ V, unsigned short* __restrict__ Vt)
{
    __shared__ unsigned short T[64][65];
    const int b = blockIdx.z;
    const int c0 = blockIdx.x * 64, m0 = blockIdx.y * 64;
    const int tid = threadIdx.x;
    const unsigned short* src = V + ((size_t)b * 512 + m0) * 1280 + c0;
    for (int it = 0; it < 16; ++it) {
        int idx = it * 256 + tid;
        int r = idx >> 6, c = idx & 63;
        T[r][c] = src[(size_t)r * 1280 + c];
    }
    __syncthreads();
    unsigned short* dst = Vt + ((size_t)b * 1280 + c0) * 512 + m0;
    for (int it = 0; it < 16; ++it) {
        int idx = it * 256 + tid;
        int r = idx >> 6, c = idx & 63;
        dst[(size_t)r * 512 + c] = T[c][r];
    }
}

// ---------------------------------------------------------------------------
extern "C" void kernel_launch(void* const* d_in, const int* in_sizes, int n_in,
                              void* d_out, int out_size, void* d_ws, size_t ws_size,
                              hipStream_t stream)
{
    const float* x   = (const float*)d_in[0];
    const int*  Mask = (const int*)d_in[1];
    const float* Wq  = (const float*)d_in[2];
    const float* bq  = (const float*)d_in[3];
    const float* Wk  = (const float*)d_in[4];
    const float* bk  = (const float*)d_in[5];
    const float* Wv  = (const float*)d_in[6];
    const float* bv  = (const float*)d_in[7];
    const float* Wr  = (const float*)d_in[8];
    const float* br  = (const float*)d_in[9];

    constexpr int N = 512, C = 1280;
    constexpr long MN = 32768;   // B*N

    char* ws = (char*)d_ws;
    unsigned short* xb = (unsigned short*)ws;                         // MN*C bf16 (later: att)
    unsigned short* Wt = (unsigned short*)(ws + 83886080);            // 4*C*C bf16
    unsigned short* Q  = (unsigned short*)(ws + 83886080 + 13107200); // MN*C (later: Vt)
    unsigned short* Km = Q + 41943040;
    unsigned short* V  = Km + 41943040;
    unsigned short* Sp = V + 41943040;                                // B*N*N
    unsigned short* Pt = Sp + 16777216;                               // B*N*N
    unsigned short* Vt = Q;     // alias: Q dead after scores GEMM
    unsigned short* att = xb;   // alias: xb dead after QKV GEMMs

    const float scale = 0.02795084971874737f;   // 1/sqrt(1280)

    transpose_w<<<dim3(20, 20, 4), 256, 0, stream>>>(Wq, Wk, Wv, Wr, Wt);
    cast_x<<<dim3(20480), 256, 0, stream>>>(x, xb, MN * C);

    // fused QKV projections: M=32768, N=3x1280, K=1280; tn/5 selects group
    gemm256<0, 1><<<dim3(15, 128, 1), 512, 0, stream>>>(xb, Wt, (void*)Q, bq, bk, bv,
        nullptr, C, C, C, C, 0, 1638400L, 41943040L, 0, 0.f);

    // scores: S'[b][i][j] = scale * (Q[b][i] . K[b][j]), masked
    gemm256<1, 0><<<dim3(2, 2, 64), 512, 0, stream>>>(Q, Km, (void*)Sp, nullptr, nullptr, nullptr,
        Mask, C, C, C, N, (long)N * C, (long)N * C, (long)N * N, (long)N * N, scale);

    // softmax rows + transposed store Pt[b][n][m]
    softmax_t<<<dim3(8, 64), 256, 0, stream>>>(Sp, Pt);

    // Vt[b][c][m]
    transpose_v<<<dim3(20, 8, 64), 256, 0, stream>>>(V, Vt);

    // att[b][n][c] = sum_m Pt[b][n][m] * Vt[b][c][m]   (M=512, N=1280, K=512)
    gemm256<2, 0><<<dim3(5, 2, 64), 512, 0, stream>>>(Pt, Vt, (void*)att, nullptr, nullptr, nullptr,
        nullptr, N, N, N, C, (long)N * N, (long)C * N, (long)N * C, 0, 0.f);

    // out = att @ Wr + br   (f32)
    gemm256<3, 0><<<dim3(5, 128, 1), 512, 0, stream>>>(att, Wt + 3 * 1638400, d_out, br, nullptr, nullptr,
        nullptr, C, C, C, C, 0, 0, 0, 0, 0.f);
}